// Round 5
// baseline (238.809 us; speedup 1.0000x reference)
//
#include <hip/hip_runtime.h>
#include <hip/hip_bf16.h>

#define NN 4096
#define LOG2E 1.44269504088896340736f
#define SPLITS 16

typedef __attribute__((ext_vector_type(8))) short s8v;   // 8 x bf16
typedef __attribute__((ext_vector_type(4))) float f4v;   // mfma accumulator

__device__ __forceinline__ unsigned fu(float x){ union{float f;unsigned u;}z; z.f=x; return z.u; }
// pack two floats to bf16x2 by truncation (bias cancels in acc/l ratio)
__device__ __forceinline__ unsigned pack2(float a, float b){
  return __builtin_amdgcn_perm(fu(b), fu(a), 0x07060302u);
}
__device__ __forceinline__ unsigned short f2bf_rne(float x){
  unsigned u = fu(x);
  u += 0x7fffu + ((u >> 16) & 1u);
  return (unsigned short)(u >> 16);
}

// Kernel 1: h = x@W (fp32), write Vf in MFMA-fragment order (bf16),
// el' (x LOG2E) and factorized exponentials Qr=exp2(er'), Sr=exp2(0.2*er').
// Vf layout: chunk(h, jblk, nf, lane) of 8 bf16 = V[jblk*32 + (lane>>4)*8 + e][h*64 + nf*16 + (lane&15)]
// so a B-fragment load in k2 is base + lane*16B -- fully coalesced 1KB.
__global__ __launch_bounds__(256) void k1_proj(
    const float* __restrict__ x, const float* __restrict__ W,
    const float* __restrict__ a, unsigned short* __restrict__ Vf,
    float* __restrict__ el4, float* __restrict__ Qr, float* __restrict__ Sr)
{
  __shared__ float4 xs[512];           // 8 rows x 256 cols fp32
  const int t = threadIdx.x;
  const int r0 = blockIdx.x * 8;
  const float4* xg = (const float4*)(x + (size_t)r0 * 256);
  xs[t] = xg[t];
  xs[t + 256] = xg[t + 256];
  __syncthreads();

  float acc[8] = {0.f,0.f,0.f,0.f,0.f,0.f,0.f,0.f};
  const float* Wp = W + t;             // column c = t
  float w0 = Wp[0], w1 = Wp[256], w2 = Wp[512], w3 = Wp[768];
  #pragma unroll 1
  for (int k4 = 0; k4 < 64; ++k4) {
    const int kn = (k4 + 1) & 63;      // wrap: last prefetch reads valid memory
    float nw0 = Wp[kn*1024 +   0];
    float nw1 = Wp[kn*1024 + 256];
    float nw2 = Wp[kn*1024 + 512];
    float nw3 = Wp[kn*1024 + 768];
    #pragma unroll
    for (int r = 0; r < 8; ++r) {
      float4 xv = xs[r*64 + k4];       // broadcast LDS read
      acc[r] = fmaf(xv.x, w0, acc[r]);
      acc[r] = fmaf(xv.y, w1, acc[r]);
      acc[r] = fmaf(xv.z, w2, acc[r]);
      acc[r] = fmaf(xv.w, w3, acc[r]);
    }
    w0 = nw0; w1 = nw1; w2 = nw2; w3 = nw3;
  }

  // Vf write: thread t holds V[r0..r0+7][c=t] -> exactly one fragment chunk
  union { unsigned u[4]; s8v v; } pk;
  #pragma unroll
  for (int p = 0; p < 4; ++p)
    pk.u[p] = (unsigned)f2bf_rne(acc[2*p]) | ((unsigned)f2bf_rne(acc[2*p+1]) << 16);
  {
    const int hh = t >> 6, nf = (t >> 4) & 3, mm = t & 15;
    const int jblk = r0 >> 5, qq = (r0 >> 3) & 3;
    const size_t chunk = (size_t)(((hh * 128 + jblk) * 4 + nf) * 64 + qq * 16 + mm);
    *(s8v*)(Vf + chunk * 8) = pk.v;
  }

  // el/er: wave w == head h; lane f = t&63
  const int f = t & 63, h = t >> 6;
  const float al = a[f], ar = a[64 + f];
  #pragma unroll
  for (int r = 0; r < 8; ++r) {
    float v = acc[r] * al;
    float u = acc[r] * ar;
    #pragma unroll
    for (int off = 32; off > 0; off >>= 1) {
      v += __shfl_xor(v, off);
      u += __shfl_xor(u, off);
    }
    if (f == 0) {
      el4[(r0 + r) * 4 + h] = v * LOG2E;                     // [i][h] (x LOG2E)
      float up = u * LOG2E;
      Qr[h * NN + (r0 + r)] = __builtin_amdgcn_exp2f(up);        // [h][j]
      Sr[h * NN + (r0 + r)] = __builtin_amdgcn_exp2f(0.2f * up); // [h][j]
    }
  }
}

// Kernel 2: fused mask+lrelu+exp (factorized) + PV GEMM via MFMA.
// grid (64 i-tiles of 64 rows, 16 splits of 256 j), block 256 = 4 waves.
// wave w owns rows i0+16w..+15, ALL 4 heads; 4 waves share the j-window
// (Vf/Qr/Sr lines shared via L1). No LDS, no barriers, no merge.
// lane: m = l&15 (row), q = l>>4 (k-quad). B-frag loads fully coalesced (Vf).
__global__ __launch_bounds__(256, 3) void k2_attn(
    const float* __restrict__ adj, const unsigned short* __restrict__ Vf,
    const float* __restrict__ el4, const float* __restrict__ Qr,
    const float* __restrict__ Sr, float* __restrict__ accP,
    float* __restrict__ lP)
{
  const int t = threadIdx.x;
  const int w = t >> 6, l = t & 63;
  const int m = l & 15, q = l >> 4;
  const int i0 = blockIdx.x * 64;
  const int split = blockIdx.y;
  const int i = i0 + w * 16 + m;
  const int jwin = split * 256;

  float4 elv = *(const float4*)(el4 + i * 4);
  const float P[4] = { __builtin_amdgcn_exp2f(elv.x), __builtin_amdgcn_exp2f(elv.y),
                       __builtin_amdgcn_exp2f(elv.z), __builtin_amdgcn_exp2f(elv.w) };
  const float R[4] = { __builtin_amdgcn_exp2f(0.2f*elv.x), __builtin_amdgcn_exp2f(0.2f*elv.y),
                       __builtin_amdgcn_exp2f(0.2f*elv.z), __builtin_amdgcn_exp2f(0.2f*elv.w) };

  f4v acc[4][4];
  #pragma unroll
  for (int h = 0; h < 4; ++h)
    #pragma unroll
    for (int nf = 0; nf < 4; ++nf)
      acc[h][nf] = (f4v){0.f, 0.f, 0.f, 0.f};
  f4v accL[4] = {(f4v){0.f,0.f,0.f,0.f},(f4v){0.f,0.f,0.f,0.f},
                 (f4v){0.f,0.f,0.f,0.f},(f4v){0.f,0.f,0.f,0.f}};

  union { unsigned u[4]; s8v v; } ones;   // all-ones bf16 B: row-sum trick for l
  #pragma unroll
  for (int p = 0; p < 4; ++p) ones.u[p] = 0x3F803F80u;

  const float* arow = adj + (size_t)i * NN + jwin + q * 8;
  const s8v* vfp = (const s8v*)Vf;

  #pragma unroll 1
  for (int jc = 0; jc < 8; ++jc) {
    const int j0 = jwin + jc * 32 + q * 8;
    float4 a0 = *(const float4*)(arow + jc * 32);
    float4 a1 = *(const float4*)(arow + jc * 32 + 4);

    #pragma unroll
    for (int h = 0; h < 4; ++h) {
      const float* qp = Qr + h * NN + j0;
      const float* sp = Sr + h * NN + j0;
      float4 q0  = *(const float4*)(qp);
      float4 q1  = *(const float4*)(qp + 4);
      float4 sv0 = *(const float4*)(sp);
      float4 sv1 = *(const float4*)(sp + 4);
      const float Ph = P[h], Rh = R[h];
      float s0 = a0.x * fmaxf(Ph * q0.x, Rh * sv0.x);
      float s1 = a0.y * fmaxf(Ph * q0.y, Rh * sv0.y);
      float s2 = a0.z * fmaxf(Ph * q0.z, Rh * sv0.z);
      float s3 = a0.w * fmaxf(Ph * q0.w, Rh * sv0.w);
      float s4 = a1.x * fmaxf(Ph * q1.x, Rh * sv1.x);
      float s5 = a1.y * fmaxf(Ph * q1.y, Rh * sv1.y);
      float s6 = a1.z * fmaxf(Ph * q1.z, Rh * sv1.z);
      float s7 = a1.w * fmaxf(Ph * q1.w, Rh * sv1.w);
      union { unsigned u[4]; s8v v; } A;   // A-frag: row m, k = q*8+idx
      A.u[0] = pack2(s0, s1);
      A.u[1] = pack2(s2, s3);
      A.u[2] = pack2(s4, s5);
      A.u[3] = pack2(s6, s7);
      // coalesced B-frag: chunk block (h, jblk=split*8+jc, nf), lane offset l
      const s8v* vb = vfp + ((size_t)((h * 128 + split * 8 + jc) * 4)) * 64 + l;
      #pragma unroll
      for (int nf = 0; nf < 4; ++nf) {
        s8v B = vb[nf * 64];
        acc[h][nf] = __builtin_amdgcn_mfma_f32_16x16x32_bf16(A.v, B, acc[h][nf], 0, 0, 0);
      }
      accL[h] = __builtin_amdgcn_mfma_f32_16x16x32_bf16(A.v, ones.v, accL[h], 0, 0, 0);
    }
  }

  // l partials; C/D layout: col = m, row = q*4 + r; m==0 lanes hold 16 rows
  if (m == 0) {
    #pragma unroll
    for (int h = 0; h < 4; ++h)
      #pragma unroll
      for (int r = 0; r < 4; ++r) {
        int row = i0 + w * 16 + q * 4 + r;
        lP[((size_t)split * NN + row) * 4 + h] = accL[h][r];
      }
  }
  float* ap = accP + (size_t)split * NN * 256;
  #pragma unroll
  for (int h = 0; h < 4; ++h)
    #pragma unroll
    for (int nf = 0; nf < 4; ++nf)
      #pragma unroll
      for (int r = 0; r < 4; ++r) {
        int row = i0 + w * 16 + q * 4 + r;
        int col = h * 64 + nf * 16 + m;
        ap[(size_t)row * 256 + col] = acc[h][nf][r];
      }
}

// Kernel 3: combine split partials, divide by l, mean over heads.
__global__ __launch_bounds__(256) void k3_reduce(
    const float* __restrict__ accP, const float* __restrict__ lP,
    float* __restrict__ out)
{
  int tid = blockIdx.x * 256 + threadIdx.x;  // 262144 threads
  int i = tid >> 6, f = tid & 63;
  float o = 0.f;
  #pragma unroll
  for (int h = 0; h < 4; ++h) {
    float sa = 0.f, sl = 0.f;
    #pragma unroll
    for (int s = 0; s < SPLITS; ++s)
      sa += accP[((size_t)s * NN + i) * 256 + h * 64 + f];
    #pragma unroll
    for (int s = 0; s < SPLITS; ++s)
      sl += lP[((size_t)s * NN + i) * 4 + h];
    o += sa / sl;   // sl > 0 guaranteed: diagonal of adj is 1
  }
  out[tid] = 0.25f * o;
}

extern "C" void kernel_launch(void* const* d_in, const int* in_sizes, int n_in,
                              void* d_out, int out_size, void* d_ws, size_t ws_size,
                              hipStream_t stream) {
  const float* x   = (const float*)d_in[0];   // (4096, 256)
  const float* adj = (const float*)d_in[1];   // (4096, 4096)
  const float* W   = (const float*)d_in[2];   // (256, 256)
  const float* a   = (const float*)d_in[3];   // (128, 1)
  float* out = (float*)d_out;                 // (4096, 64)

  char* ws = (char*)d_ws;
  unsigned short* Vf = (unsigned short*)ws;                       // 2 MB  bf16 fragment-ordered
  float* el4 = (float*)(ws + (2u << 20));                         // 64 KB [4096][4]
  float* Qr  = (float*)(ws + (2u << 20) + (64u << 10));           // 64 KB [4][4096]
  float* Sr  = (float*)(ws + (2u << 20) + (128u << 10));          // 64 KB [4][4096]
  float* lP  = (float*)(ws + (2u << 20) + (192u << 10));          // 1 MB  [16][4096][4]
  float* accP= (float*)(ws + (3u << 20) + (192u << 10));          // 64 MB [16][4096][256]

  k1_proj<<<512, 256, 0, stream>>>(x, W, a, Vf, el4, Qr, Sr);
  k2_attn<<<dim3(64, SPLITS), 256, 0, stream>>>(adj, Vf, el4, Qr, Sr, accP, lP);
  k3_reduce<<<1024, 256, 0, stream>>>(accP, lP, out);
}

// Round 6
// 181.303 us; speedup vs baseline: 1.3172x; 1.3172x over previous
//
#include <hip/hip_runtime.h>
#include <hip/hip_bf16.h>

#define NN 4096
#define LOG2E 1.44269504088896340736f
#define SPLITS 16

typedef __attribute__((ext_vector_type(8))) short s8v;   // 8 x bf16
typedef __attribute__((ext_vector_type(4))) float f4v;   // mfma accumulator

__device__ __forceinline__ unsigned fu(float x){ union{float f;unsigned u;}z; z.f=x; return z.u; }
__device__ __forceinline__ unsigned short f2bf_rne(float x){
  unsigned u = fu(x);
  u += 0x7fffu + ((u >> 16) & 1u);
  return (unsigned short)(u >> 16);
}
// RNE pack two floats -> bf16x2 (bias must not survive: l is folded pre-MFMA now)
__device__ __forceinline__ unsigned pack2_rne(float a, float b){
  return (unsigned)f2bf_rne(a) | ((unsigned)f2bf_rne(b) << 16);
}

// Kernel 1: h = x@W (fp32), write Vf in MFMA-fragment order (bf16),
// el' (x LOG2E) and factorized exponentials Qr=exp2(er'), Sr=exp2(0.2*er').
__global__ __launch_bounds__(256) void k1_proj(
    const float* __restrict__ x, const float* __restrict__ W,
    const float* __restrict__ a, unsigned short* __restrict__ Vf,
    float* __restrict__ el4, float* __restrict__ Qr, float* __restrict__ Sr)
{
  __shared__ float4 xs[512];           // 8 rows x 256 cols fp32
  const int t = threadIdx.x;
  const int r0 = blockIdx.x * 8;
  const float4* xg = (const float4*)(x + (size_t)r0 * 256);
  xs[t] = xg[t];
  xs[t + 256] = xg[t + 256];
  __syncthreads();

  float acc[8] = {0.f,0.f,0.f,0.f,0.f,0.f,0.f,0.f};
  const float* Wp = W + t;             // column c = t
  float w0 = Wp[0], w1 = Wp[256], w2 = Wp[512], w3 = Wp[768];
  #pragma unroll 1
  for (int k4 = 0; k4 < 64; ++k4) {
    const int kn = (k4 + 1) & 63;
    float nw0 = Wp[kn*1024 +   0];
    float nw1 = Wp[kn*1024 + 256];
    float nw2 = Wp[kn*1024 + 512];
    float nw3 = Wp[kn*1024 + 768];
    #pragma unroll
    for (int r = 0; r < 8; ++r) {
      float4 xv = xs[r*64 + k4];       // broadcast LDS read
      acc[r] = fmaf(xv.x, w0, acc[r]);
      acc[r] = fmaf(xv.y, w1, acc[r]);
      acc[r] = fmaf(xv.z, w2, acc[r]);
      acc[r] = fmaf(xv.w, w3, acc[r]);
    }
    w0 = nw0; w1 = nw1; w2 = nw2; w3 = nw3;
  }

  // Vf write: thread t holds V[r0..r0+7][c=t] -> exactly one fragment chunk
  union { unsigned u[4]; s8v v; } pk;
  #pragma unroll
  for (int p = 0; p < 4; ++p)
    pk.u[p] = pack2_rne(acc[2*p], acc[2*p+1]);
  {
    const int hh = t >> 6, nf = (t >> 4) & 3, mm = t & 15;
    const int jblk = r0 >> 5, qq = (r0 >> 3) & 3;
    const size_t chunk = (size_t)(((hh * 128 + jblk) * 4 + nf) * 64 + qq * 16 + mm);
    *(s8v*)(Vf + chunk * 8) = pk.v;
  }

  // el/er: wave w == head h; lane f = t&63
  const int f = t & 63, h = t >> 6;
  const float al = a[f], ar = a[64 + f];
  #pragma unroll
  for (int r = 0; r < 8; ++r) {
    float v = acc[r] * al;
    float u = acc[r] * ar;
    #pragma unroll
    for (int off = 32; off > 0; off >>= 1) {
      v += __shfl_xor(v, off);
      u += __shfl_xor(u, off);
    }
    if (f == 0) {
      el4[(r0 + r) * 4 + h] = v * LOG2E;                     // [i][h] (x LOG2E)
      float up = u * LOG2E;
      Qr[h * NN + (r0 + r)] = __builtin_amdgcn_exp2f(up);        // [h][j]
      Sr[h * NN + (r0 + r)] = __builtin_amdgcn_exp2f(0.2f * up); // [h][j]
    }
  }
}

// Kernel 0L: pack adj to bits (one pass over the 64MB, fully coalesced) AND
// compute softmax denominators l[i,h] = sum_j adj*max(P*Q, R*S) in the same
// sweep; write premultiplied PL = P/l, RL = R/l.
// grid 1024 blocks x 256 thr; block = 4 waves, wave = 1 row of adj.
__global__ __launch_bounds__(256) void k0_pack(
    const float* __restrict__ adj, const float* __restrict__ el4,
    const float* __restrict__ Qr, const float* __restrict__ Sr,
    unsigned long long* __restrict__ adjP64,
    float* __restrict__ PL, float* __restrict__ RL)
{
  const int t = threadIdx.x;
  const int w = t >> 6, l = t & 63;
  const int row = blockIdx.x * 4 + w;
  const float* arow = adj + (size_t)row * NN;

  float4 elv = *(const float4*)(el4 + row * 4);   // broadcast
  const float P[4] = { __builtin_amdgcn_exp2f(elv.x), __builtin_amdgcn_exp2f(elv.y),
                       __builtin_amdgcn_exp2f(elv.z), __builtin_amdgcn_exp2f(elv.w) };
  const float R[4] = { __builtin_amdgcn_exp2f(0.2f*elv.x), __builtin_amdgcn_exp2f(0.2f*elv.y),
                       __builtin_amdgcn_exp2f(0.2f*elv.z), __builtin_amdgcn_exp2f(0.2f*elv.w) };
  float lsum[4] = {0.f, 0.f, 0.f, 0.f};

  // depth-1 software pipeline on the adj stream (coalesced 256B per load)
  float af[4], nf_[4];
  #pragma unroll
  for (int k = 0; k < 4; ++k) af[k] = arow[k * 64 + l];

  #pragma unroll 1
  for (int p = 0; p < 16; ++p) {
    const int nbase = (p < 15) ? (p + 1) * 256 : 0;
    #pragma unroll
    for (int k = 0; k < 4; ++k) nf_[k] = arow[nbase + k * 64 + l];

    const int base = p * 256;
    unsigned long long bm[4];
    #pragma unroll
    for (int k = 0; k < 4; ++k) {
      bm[k] = __ballot(af[k] != 0.0f);
      const int j = base + k * 64 + l;
      #pragma unroll
      for (int h = 0; h < 4; ++h) {
        float qv = Qr[h * NN + j];
        float sv = Sr[h * NN + j];
        lsum[h] = fmaf(af[k], fmaxf(P[h] * qv, R[h] * sv), lsum[h]);
      }
    }
    if (l == 0) {
      unsigned long long* dst = adjP64 + (size_t)row * 64 + p * 4;
      dst[0] = bm[0]; dst[1] = bm[1]; dst[2] = bm[2]; dst[3] = bm[3];
    }
    #pragma unroll
    for (int k = 0; k < 4; ++k) af[k] = nf_[k];
  }

  // reduce lsum across 64 lanes
  #pragma unroll
  for (int h = 0; h < 4; ++h) {
    float v = lsum[h];
    #pragma unroll
    for (int off = 32; off > 0; off >>= 1) v += __shfl_xor(v, off);
    lsum[h] = v;
  }
  if (l < 4) {
    float li = 1.0f / lsum[l];    // l > 0: diagonal of adj is 1
    PL[row * 4 + l] = P[l] * li;
    RL[row * 4 + l] = R[l] * li;
  }
}

// Kernel 2: masked-softmax-weighted PV via MFMA, heads FOLDED into one
// accumulator (s pre-divided by l). grid (64 i-tiles, 16 splits of 256 j),
// block 256 = 4 waves; wave w: rows i0+16w..+15, all heads.
// lane: m = l&15 (row), q = l>>4 (k-quad). All global loads coalesced or tiny.
__global__ __launch_bounds__(256, 4) void k2_attn(
    const unsigned* __restrict__ adjP, const unsigned short* __restrict__ Vf,
    const float* __restrict__ PL, const float* __restrict__ RL,
    const float* __restrict__ Qr, const float* __restrict__ Sr,
    float* __restrict__ accF)
{
  __shared__ float qs[2048];           // 8KB: cell(h,jc,q)=16 floats {Q[8],S[8]}
  const int t = threadIdx.x;
  const int w = t >> 6, l = t & 63;
  const int m = l & 15, q = l >> 4;
  const int i0 = blockIdx.x * 64;
  const int split = blockIdx.y;
  const int i = i0 + w * 16 + m;
  const int jwin = split * 256;

  // stage Q/S window to LDS: thread (h = t>>6, lane) loads float4 of 4 j's
  {
    const int h = t >> 6;
    float4 qv = *(const float4*)(Qr + h * NN + jwin + l * 4);
    float4 sv = *(const float4*)(Sr + h * NN + jwin + l * 4);
    const int jc = l >> 3, qq = (l >> 1) & 3, hp = (l & 1) * 4;
    float* cell = qs + ((h * 8 + jc) * 4 + qq) * 16;
    *(float4*)(cell + hp) = qv;
    *(float4*)(cell + 8 + hp) = sv;
  }

  float4 pl4 = *(const float4*)(PL + i * 4);
  float4 rl4 = *(const float4*)(RL + i * 4);
  const float Pl[4] = {pl4.x, pl4.y, pl4.z, pl4.w};
  const float Rl[4] = {rl4.x, rl4.y, rl4.z, rl4.w};

  // adj bits for this row's window: 8 words (256 bits)
  union { uint4 v[2]; unsigned u[8]; } aw;
  {
    const uint4* ap = (const uint4*)(adjP + (size_t)i * 128 + split * 8);
    aw.v[0] = ap[0];
    aw.v[1] = ap[1];
  }

  f4v acc[4];
  #pragma unroll
  for (int nf = 0; nf < 4; ++nf) acc[nf] = (f4v){0.f, 0.f, 0.f, 0.f};

  __syncthreads();

  #pragma unroll 1
  for (int jc = 0; jc < 8; ++jc) {
    const unsigned byte = (aw.u[jc] >> (q * 8)) & 0xFFu;
    float bitf[8];
    #pragma unroll
    for (int e = 0; e < 8; ++e)
      bitf[e] = (float)((byte >> e) & 1u);

    #pragma unroll
    for (int h = 0; h < 4; ++h) {
      const float* cell = qs + ((h * 8 + jc) * 4 + q) * 16;
      float4 q0  = *(const float4*)(cell);
      float4 q1  = *(const float4*)(cell + 4);
      float4 sv0 = *(const float4*)(cell + 8);
      float4 sv1 = *(const float4*)(cell + 12);
      const float Ph = Pl[h], Rh = Rl[h];
      float s0 = bitf[0] * fmaxf(Ph * q0.x, Rh * sv0.x);
      float s1 = bitf[1] * fmaxf(Ph * q0.y, Rh * sv0.y);
      float s2 = bitf[2] * fmaxf(Ph * q0.z, Rh * sv0.z);
      float s3 = bitf[3] * fmaxf(Ph * q0.w, Rh * sv0.w);
      float s4 = bitf[4] * fmaxf(Ph * q1.x, Rh * sv1.x);
      float s5 = bitf[5] * fmaxf(Ph * q1.y, Rh * sv1.y);
      float s6 = bitf[6] * fmaxf(Ph * q1.z, Rh * sv1.z);
      float s7 = bitf[7] * fmaxf(Ph * q1.w, Rh * sv1.w);
      union { unsigned u[4]; s8v v; } A;   // A-frag: row m, k = q*8+idx
      A.u[0] = pack2_rne(s0, s1);
      A.u[1] = pack2_rne(s2, s3);
      A.u[2] = pack2_rne(s4, s5);
      A.u[3] = pack2_rne(s6, s7);
      const s8v* vb = (const s8v*)Vf + ((size_t)((h * 128 + split * 8 + jc) * 4)) * 64 + l;
      #pragma unroll
      for (int nf = 0; nf < 4; ++nf) {
        s8v B = vb[nf * 64];             // coalesced 1KB fragment load
        acc[nf] = __builtin_amdgcn_mfma_f32_16x16x32_bf16(A.v, B, acc[nf], 0, 0, 0);
      }
    }
  }

  // epilogue: raw register-layout store, fully coalesced 256B per store
  const size_t wbase = ((size_t)(split * 64 + blockIdx.x) * 4 + w) * 1024;
  #pragma unroll
  for (int nf = 0; nf < 4; ++nf)
    #pragma unroll
    for (int r = 0; r < 4; ++r)
      accF[wbase + (nf * 4 + r) * 64 + l] = acc[nf][r];
}

// Kernel 3: sum 16 splits (coalesced), decode fragment layout, write out/4.
__global__ __launch_bounds__(256) void k3_reduce(
    const float* __restrict__ accF, float* __restrict__ out)
{
  const int pos = blockIdx.x * 256 + threadIdx.x;   // 262144 positions
  float s = 0.f;
  #pragma unroll
  for (int sp = 0; sp < SPLITS; ++sp)
    s += accF[(size_t)sp * 262144 + pos];
  const int l = pos & 63, r = (pos >> 6) & 3, nf = (pos >> 8) & 3;
  const int w = (pos >> 10) & 3, bx = pos >> 12;
  const int row = bx * 64 + w * 16 + (l >> 4) * 4 + r;
  const int col = nf * 16 + (l & 15);
  out[row * 64 + col] = 0.25f * s;
}

extern "C" void kernel_launch(void* const* d_in, const int* in_sizes, int n_in,
                              void* d_out, int out_size, void* d_ws, size_t ws_size,
                              hipStream_t stream) {
  const float* x   = (const float*)d_in[0];   // (4096, 256)
  const float* adj = (const float*)d_in[1];   // (4096, 4096)
  const float* W   = (const float*)d_in[2];   // (256, 256)
  const float* a   = (const float*)d_in[3];   // (128, 1)
  float* out = (float*)d_out;                 // (4096, 64)

  char* ws = (char*)d_ws;
  unsigned short* Vf = (unsigned short*)ws;                  // 2 MB  bf16 fragment-ordered
  float* el4 = (float*)(ws + (2u << 20));                    // 64 KB [4096][4]
  float* Qr  = (float*)(ws + (2u << 20) + (64u << 10));      // 64 KB [4][4096]
  float* Sr  = (float*)(ws + (2u << 20) + (128u << 10));     // 64 KB [4][4096]
  float* PLp = (float*)(ws + (2u << 20) + (192u << 10));     // 64 KB [4096][4]
  float* RLp = (float*)(ws + (2u << 20) + (256u << 10));     // 64 KB [4096][4]
  unsigned long long* adjP64 = (unsigned long long*)(ws + (2u << 20) + (320u << 10)); // 2 MB bits
  float* accF = (float*)(ws + (4u << 20) + (320u << 10));    // 16 MB [16][262144]

  k1_proj<<<512, 256, 0, stream>>>(x, W, a, Vf, el4, Qr, Sr);
  k0_pack<<<1024, 256, 0, stream>>>(adj, el4, Qr, Sr, adjP64, PLp, RLp);
  k2_attn<<<dim3(64, SPLITS), 256, 0, stream>>>((const unsigned*)adjP64, Vf, PLp, RLp,
                                                Qr, Sr, accF);
  k3_reduce<<<1024, 256, 0, stream>>>(accF, out);
}

// Round 7
// 175.370 us; speedup vs baseline: 1.3617x; 1.0338x over previous
//
#include <hip/hip_runtime.h>
#include <hip/hip_bf16.h>

#define NN 4096
#define LOG2E 1.44269504088896340736f
#define SPLITS 16

typedef __attribute__((ext_vector_type(8))) short s8v;   // 8 x bf16
typedef __attribute__((ext_vector_type(4))) float f4v;   // mfma accumulator

__device__ __forceinline__ unsigned fu(float x){ union{float f;unsigned u;}z; z.f=x; return z.u; }
__device__ __forceinline__ unsigned short f2bf_rne(float x){
  unsigned u = fu(x);
  u += 0x7fffu + ((u >> 16) & 1u);
  return (unsigned short)(u >> 16);
}
__device__ __forceinline__ unsigned pack2_rne(float a, float b){
  return (unsigned)f2bf_rne(a) | ((unsigned)f2bf_rne(b) << 16);
}

// Kernel 1: h = x@W (fp32), write Vf in MFMA-fragment order (bf16),
// el' (x LOG2E) and factorized exponentials Qr=exp2(er'), Sr=exp2(0.2*er').
__global__ __launch_bounds__(256) void k1_proj(
    const float* __restrict__ x, const float* __restrict__ W,
    const float* __restrict__ a, unsigned short* __restrict__ Vf,
    float* __restrict__ el4, float* __restrict__ Qr, float* __restrict__ Sr)
{
  __shared__ float4 xs[512];           // 8 rows x 256 cols fp32
  const int t = threadIdx.x;
  const int r0 = blockIdx.x * 8;
  const float4* xg = (const float4*)(x + (size_t)r0 * 256);
  xs[t] = xg[t];
  xs[t + 256] = xg[t + 256];
  __syncthreads();

  float acc[8] = {0.f,0.f,0.f,0.f,0.f,0.f,0.f,0.f};
  const float* Wp = W + t;             // column c = t
  float w0 = Wp[0], w1 = Wp[256], w2 = Wp[512], w3 = Wp[768];
  #pragma unroll 1
  for (int k4 = 0; k4 < 64; ++k4) {
    const int kn = (k4 + 1) & 63;
    float nw0 = Wp[kn*1024 +   0];
    float nw1 = Wp[kn*1024 + 256];
    float nw2 = Wp[kn*1024 + 512];
    float nw3 = Wp[kn*1024 + 768];
    #pragma unroll
    for (int r = 0; r < 8; ++r) {
      float4 xv = xs[r*64 + k4];       // broadcast LDS read
      acc[r] = fmaf(xv.x, w0, acc[r]);
      acc[r] = fmaf(xv.y, w1, acc[r]);
      acc[r] = fmaf(xv.z, w2, acc[r]);
      acc[r] = fmaf(xv.w, w3, acc[r]);
    }
    w0 = nw0; w1 = nw1; w2 = nw2; w3 = nw3;
  }

  // Vf write: thread t holds V[r0..r0+7][c=t] -> exactly one fragment chunk
  union { unsigned u[4]; s8v v; } pk;
  #pragma unroll
  for (int p = 0; p < 4; ++p)
    pk.u[p] = pack2_rne(acc[2*p], acc[2*p+1]);
  {
    const int hh = t >> 6, nf = (t >> 4) & 3, mm = t & 15;
    const int jblk = r0 >> 5, qq = (r0 >> 3) & 3;
    const size_t chunk = (size_t)(((hh * 128 + jblk) * 4 + nf) * 64 + qq * 16 + mm);
    *(s8v*)(Vf + chunk * 8) = pk.v;
  }

  // el/er: wave w == head h; lane f = t&63
  const int f = t & 63, h = t >> 6;
  const float al = a[f], ar = a[64 + f];
  #pragma unroll
  for (int r = 0; r < 8; ++r) {
    float v = acc[r] * al;
    float u = acc[r] * ar;
    #pragma unroll
    for (int off = 32; off > 0; off >>= 1) {
      v += __shfl_xor(v, off);
      u += __shfl_xor(u, off);
    }
    if (f == 0) {
      el4[(r0 + r) * 4 + h] = v * LOG2E;                     // [i][h] (x LOG2E)
      float up = u * LOG2E;
      Qr[h * NN + (r0 + r)] = __builtin_amdgcn_exp2f(up);        // [h][j]
      Sr[h * NN + (r0 + r)] = __builtin_amdgcn_exp2f(0.2f * up); // [h][j]
    }
  }
}

// Kernel 0: pack adj to bits (float4 stream, ballot order: per 256-j window,
// bit for j sits in word (j&3) at position (j>>2)) AND compute softmax
// denominators l[i,h] in the same sweep; write premultiplied PL=P/l, RL=R/l.
// grid 1024 x 256; wave = 1 row; lane l owns j = p*256 + 4l .. +3.
__global__ __launch_bounds__(256, 4) void k0_pack(
    const float* __restrict__ adj, const float* __restrict__ el4,
    const float* __restrict__ Qr, const float* __restrict__ Sr,
    unsigned long long* __restrict__ adjB,
    float* __restrict__ PL, float* __restrict__ RL)
{
  const int t = threadIdx.x;
  const int w = t >> 6, l = t & 63;
  const int row = blockIdx.x * 4 + w;
  const float* arow = adj + (size_t)row * NN;

  float4 elv = *(const float4*)(el4 + row * 4);
  const float P[4] = { __builtin_amdgcn_exp2f(elv.x), __builtin_amdgcn_exp2f(elv.y),
                       __builtin_amdgcn_exp2f(elv.z), __builtin_amdgcn_exp2f(elv.w) };
  const float R[4] = { __builtin_amdgcn_exp2f(0.2f*elv.x), __builtin_amdgcn_exp2f(0.2f*elv.y),
                       __builtin_amdgcn_exp2f(0.2f*elv.z), __builtin_amdgcn_exp2f(0.2f*elv.w) };
  float lsum[4] = {0.f, 0.f, 0.f, 0.f};

  // depth-1 pipeline: all 9 float4 streams
  float4 av, qv0, qv1, qv2, qv3, sv0, sv1, sv2, sv3;
  av  = *(const float4*)(arow + l * 4);
  qv0 = *(const float4*)(Qr + 0 * NN + l * 4);
  qv1 = *(const float4*)(Qr + 1 * NN + l * 4);
  qv2 = *(const float4*)(Qr + 2 * NN + l * 4);
  qv3 = *(const float4*)(Qr + 3 * NN + l * 4);
  sv0 = *(const float4*)(Sr + 0 * NN + l * 4);
  sv1 = *(const float4*)(Sr + 1 * NN + l * 4);
  sv2 = *(const float4*)(Sr + 2 * NN + l * 4);
  sv3 = *(const float4*)(Sr + 3 * NN + l * 4);

  #pragma unroll 1
  for (int p = 0; p < 16; ++p) {
    const int nb = ((p < 15) ? (p + 1) * 256 : 0) + l * 4;
    float4 nav  = *(const float4*)(arow + nb);
    float4 nqv0 = *(const float4*)(Qr + 0 * NN + nb);
    float4 nqv1 = *(const float4*)(Qr + 1 * NN + nb);
    float4 nqv2 = *(const float4*)(Qr + 2 * NN + nb);
    float4 nqv3 = *(const float4*)(Qr + 3 * NN + nb);
    float4 nsv0 = *(const float4*)(Sr + 0 * NN + nb);
    float4 nsv1 = *(const float4*)(Sr + 1 * NN + nb);
    float4 nsv2 = *(const float4*)(Sr + 2 * NN + nb);
    float4 nsv3 = *(const float4*)(Sr + 3 * NN + nb);

    unsigned long long b0 = __ballot(av.x != 0.0f);
    unsigned long long b1 = __ballot(av.y != 0.0f);
    unsigned long long b2 = __ballot(av.z != 0.0f);
    unsigned long long b3 = __ballot(av.w != 0.0f);
    if (l == 0) {
      unsigned long long* dst = adjB + (size_t)row * 64 + p * 4;
      dst[0] = b0; dst[1] = b1; dst[2] = b2; dst[3] = b3;
    }
    #pragma unroll
    for (int h = 0; h < 4; ++h) {
      const float4 qv = (h==0)?qv0:(h==1)?qv1:(h==2)?qv2:qv3;
      const float4 sv = (h==0)?sv0:(h==1)?sv1:(h==2)?sv2:sv3;
      float m0 = fmaxf(P[h] * qv.x, R[h] * sv.x);
      float m1 = fmaxf(P[h] * qv.y, R[h] * sv.y);
      float m2 = fmaxf(P[h] * qv.z, R[h] * sv.z);
      float m3 = fmaxf(P[h] * qv.w, R[h] * sv.w);
      lsum[h] = fmaf(av.x, m0, lsum[h]);
      lsum[h] = fmaf(av.y, m1, lsum[h]);
      lsum[h] = fmaf(av.z, m2, lsum[h]);
      lsum[h] = fmaf(av.w, m3, lsum[h]);
    }
    av = nav;
    qv0 = nqv0; qv1 = nqv1; qv2 = nqv2; qv3 = nqv3;
    sv0 = nsv0; sv1 = nsv1; sv2 = nsv2; sv3 = nsv3;
  }

  #pragma unroll
  for (int h = 0; h < 4; ++h) {
    float v = lsum[h];
    #pragma unroll
    for (int off = 32; off > 0; off >>= 1) v += __shfl_xor(v, off);
    lsum[h] = v;
  }
  if (l < 4) {
    float li = 1.0f / lsum[l];    // l > 0: diagonal of adj is 1
    PL[row * 4 + l] = P[l] * li;
    RL[row * 4 + l] = R[l] * li;
  }
}

// Kernel 2: masked-softmax-weighted PV via MFMA, heads folded, atomic epilogue
// straight into out. grid (64 i-tiles, 16 splits of 256 j), block 256 = 4 waves.
// lane: m = l&15 (row), q = l>>4 (k-quad). Mask bits in ballot order:
// frag element e of (jc,q) = j = 32jc+8q+e -> word e&3, bit 8jc+2q+(e>>2).
__global__ __launch_bounds__(256, 4) void k2_attn(
    const unsigned long long* __restrict__ adjB, const unsigned short* __restrict__ Vf,
    const float* __restrict__ PL, const float* __restrict__ RL,
    const float* __restrict__ Qr, const float* __restrict__ Sr,
    float* __restrict__ out)
{
  __shared__ float qs[2048];           // 8KB: cell(h,jc,q)=16 floats {Q[8],S[8]}
  const int t = threadIdx.x;
  const int w = t >> 6, l = t & 63;
  const int m = l & 15, q = l >> 4;
  const int i0 = blockIdx.x * 64;
  const int split = blockIdx.y;
  const int i = i0 + w * 16 + m;
  const int jwin = split * 256;

  // stage Q/S window to LDS
  {
    const int h = t >> 6;
    float4 qv = *(const float4*)(Qr + h * NN + jwin + l * 4);
    float4 sv = *(const float4*)(Sr + h * NN + jwin + l * 4);
    const int jc = l >> 3, qq = (l >> 1) & 3, hp = (l & 1) * 4;
    float* cell = qs + ((h * 8 + jc) * 4 + qq) * 16;
    *(float4*)(cell + hp) = qv;
    *(float4*)(cell + 8 + hp) = sv;
  }

  float4 pl4 = *(const float4*)(PL + i * 4);
  float4 rl4 = *(const float4*)(RL + i * 4);
  const float Pl[4] = {pl4.x, pl4.y, pl4.z, pl4.w};
  const float Rl[4] = {rl4.x, rl4.y, rl4.z, rl4.w};

  // window mask: 4 x 64-bit ballot words
  const unsigned long long* bp = adjB + (size_t)i * 64 + split * 4;
  unsigned long long b0 = bp[0], b1 = bp[1], b2 = bp[2], b3 = bp[3];

  f4v acc[4];
  #pragma unroll
  for (int nf = 0; nf < 4; ++nf) acc[nf] = (f4v){0.f, 0.f, 0.f, 0.f};

  const s8v* vfp = (const s8v*)Vf;
  // B-frag pipeline: preload (jc=0, h=0)
  s8v Bc[4];
  #pragma unroll
  for (int nf = 0; nf < 4; ++nf)
    Bc[nf] = vfp[(size_t)((0 * 128 + split * 8 + 0) * 4 + nf) * 64 + l];

  __syncthreads();

  #pragma unroll 1
  for (int jc = 0; jc < 8; ++jc) {
    const unsigned sh = jc * 8 + q * 2;
    const unsigned t0 = (unsigned)(b0 >> sh) & 3u;
    const unsigned t1 = (unsigned)(b1 >> sh) & 3u;
    const unsigned t2 = (unsigned)(b2 >> sh) & 3u;
    const unsigned t3 = (unsigned)(b3 >> sh) & 3u;
    float bitf[8];
    bitf[0] = (float)(t0 & 1u); bitf[4] = (float)(t0 >> 1);
    bitf[1] = (float)(t1 & 1u); bitf[5] = (float)(t1 >> 1);
    bitf[2] = (float)(t2 & 1u); bitf[6] = (float)(t2 >> 1);
    bitf[3] = (float)(t3 & 1u); bitf[7] = (float)(t3 >> 1);

    #pragma unroll
    for (int h = 0; h < 4; ++h) {
      // prefetch next (h+1, jc) or (0, jc+1) B-frags (tail reads in-bounds garbage)
      const int hn = (h < 3) ? h + 1 : 0;
      const int jcn = (h < 3) ? jc : jc + 1;
      s8v Bn[4];
      #pragma unroll
      for (int nf = 0; nf < 4; ++nf)
        Bn[nf] = vfp[(size_t)((hn * 128 + split * 8 + jcn) * 4 + nf) * 64 + l];

      const float* cell = qs + ((h * 8 + jc) * 4 + q) * 16;
      float4 q0  = *(const float4*)(cell);
      float4 q1  = *(const float4*)(cell + 4);
      float4 sv0 = *(const float4*)(cell + 8);
      float4 sv1 = *(const float4*)(cell + 12);
      const float Ph = Pl[h], Rh = Rl[h];
      float s0 = bitf[0] * fmaxf(Ph * q0.x, Rh * sv0.x);
      float s1 = bitf[1] * fmaxf(Ph * q0.y, Rh * sv0.y);
      float s2 = bitf[2] * fmaxf(Ph * q0.z, Rh * sv0.z);
      float s3 = bitf[3] * fmaxf(Ph * q0.w, Rh * sv0.w);
      float s4 = bitf[4] * fmaxf(Ph * q1.x, Rh * sv1.x);
      float s5 = bitf[5] * fmaxf(Ph * q1.y, Rh * sv1.y);
      float s6 = bitf[6] * fmaxf(Ph * q1.z, Rh * sv1.z);
      float s7 = bitf[7] * fmaxf(Ph * q1.w, Rh * sv1.w);
      union { unsigned u[4]; s8v v; } A;   // A-frag: row m, k = q*8+idx
      A.u[0] = pack2_rne(s0, s1);
      A.u[1] = pack2_rne(s2, s3);
      A.u[2] = pack2_rne(s4, s5);
      A.u[3] = pack2_rne(s6, s7);
      #pragma unroll
      for (int nf = 0; nf < 4; ++nf)
        acc[nf] = __builtin_amdgcn_mfma_f32_16x16x32_bf16(A.v, Bc[nf], acc[nf], 0, 0, 0);
      #pragma unroll
      for (int nf = 0; nf < 4; ++nf) Bc[nf] = Bn[nf];
    }
  }

  // epilogue: C/D layout col = m, row = q*4 + r; direct atomic accumulate
  #pragma unroll
  for (int nf = 0; nf < 4; ++nf)
    #pragma unroll
    for (int r = 0; r < 4; ++r) {
      int row = i0 + w * 16 + q * 4 + r;
      int col = nf * 16 + m;
      atomicAdd(&out[row * 64 + col], 0.25f * acc[nf][r]);
    }
}

extern "C" void kernel_launch(void* const* d_in, const int* in_sizes, int n_in,
                              void* d_out, int out_size, void* d_ws, size_t ws_size,
                              hipStream_t stream) {
  const float* x   = (const float*)d_in[0];   // (4096, 256)
  const float* adj = (const float*)d_in[1];   // (4096, 4096)
  const float* W   = (const float*)d_in[2];   // (256, 256)
  const float* a   = (const float*)d_in[3];   // (128, 1)
  float* out = (float*)d_out;                 // (4096, 64)

  char* ws = (char*)d_ws;
  unsigned short* Vf = (unsigned short*)ws;                  // 2 MB  bf16 fragment-ordered
  float* el4 = (float*)(ws + (2u << 20));                    // 64 KB [4096][4]
  float* Qr  = (float*)(ws + (2u << 20) + (64u << 10));      // 64 KB [4][4096]
  float* Sr  = (float*)(ws + (2u << 20) + (128u << 10));     // 64 KB [4][4096]
  float* PLp = (float*)(ws + (2u << 20) + (192u << 10));     // 64 KB [4096][4]
  float* RLp = (float*)(ws + (2u << 20) + (256u << 10));     // 64 KB [4096][4]
  unsigned long long* adjB = (unsigned long long*)(ws + (2u << 20) + (320u << 10)); // 2 MB bits

  hipMemsetAsync(out, 0, (size_t)out_size * sizeof(float), stream);
  k1_proj<<<512, 256, 0, stream>>>(x, W, a, Vf, el4, Qr, Sr);
  k0_pack<<<1024, 256, 0, stream>>>(adj, el4, Qr, Sr, adjB, PLp, RLp);
  k2_attn<<<dim3(64, SPLITS), 256, 0, stream>>>(adjB, Vf, PLp, RLp, Qr, Sr, out);
}

// Round 9
// 174.311 us; speedup vs baseline: 1.3700x; 1.0061x over previous
//
#include <hip/hip_runtime.h>
#include <hip/hip_bf16.h>

#define NN 4096
#define LOG2E 1.44269504088896340736f

typedef __attribute__((ext_vector_type(8))) short s8v;   // 8 x bf16
typedef __attribute__((ext_vector_type(4))) float f4v;   // mfma accumulator

__device__ __forceinline__ unsigned fu(float x){ union{float f;unsigned u;}z; z.f=x; return z.u; }
__device__ __forceinline__ unsigned short f2bf_rne(float x){
  unsigned u = fu(x);
  u += 0x7fffu + ((u >> 16) & 1u);
  return (unsigned short)(u >> 16);
}
__device__ __forceinline__ unsigned pack2_rne(float a, float b){
  return (unsigned)f2bf_rne(a) | ((unsigned)f2bf_rne(b) << 16);
}

// Kernel 1: h = x@W (fp32), write Vf in MFMA-fragment order (bf16),
// el' (x LOG2E) and factorized exponentials Qr=exp2(er'), Sr=exp2(0.2*er').
__global__ __launch_bounds__(256) void k1_proj(
    const float* __restrict__ x, const float* __restrict__ W,
    const float* __restrict__ a, unsigned short* __restrict__ Vf,
    float* __restrict__ el4, float* __restrict__ Qr, float* __restrict__ Sr)
{
  __shared__ float4 xs[512];           // 8 rows x 256 cols fp32
  const int t = threadIdx.x;
  const int r0 = blockIdx.x * 8;
  const float4* xg = (const float4*)(x + (size_t)r0 * 256);
  xs[t] = xg[t];
  xs[t + 256] = xg[t + 256];
  __syncthreads();

  float acc[8] = {0.f,0.f,0.f,0.f,0.f,0.f,0.f,0.f};
  const float* Wp = W + t;             // column c = t
  float w0 = Wp[0], w1 = Wp[256], w2 = Wp[512], w3 = Wp[768];
  #pragma unroll 1
  for (int k4 = 0; k4 < 64; ++k4) {
    const int kn = (k4 + 1) & 63;
    float nw0 = Wp[kn*1024 +   0];
    float nw1 = Wp[kn*1024 + 256];
    float nw2 = Wp[kn*1024 + 512];
    float nw3 = Wp[kn*1024 + 768];
    #pragma unroll
    for (int r = 0; r < 8; ++r) {
      float4 xv = xs[r*64 + k4];       // broadcast LDS read
      acc[r] = fmaf(xv.x, w0, acc[r]);
      acc[r] = fmaf(xv.y, w1, acc[r]);
      acc[r] = fmaf(xv.z, w2, acc[r]);
      acc[r] = fmaf(xv.w, w3, acc[r]);
    }
    w0 = nw0; w1 = nw1; w2 = nw2; w3 = nw3;
  }

  // Vf write: thread t holds V[r0..r0+7][c=t] -> exactly one fragment chunk
  union { unsigned u[4]; s8v v; } pk;
  #pragma unroll
  for (int p = 0; p < 4; ++p)
    pk.u[p] = pack2_rne(acc[2*p], acc[2*p+1]);
  {
    const int hh = t >> 6, nf = (t >> 4) & 3, mm = t & 15;
    const int jblk = r0 >> 5, qq = (r0 >> 3) & 3;
    const size_t chunk = (size_t)(((hh * 128 + jblk) * 4 + nf) * 64 + qq * 16 + mm);
    *(s8v*)(Vf + chunk * 8) = pk.v;
  }

  // el/er: wave w == head h; lane f = t&63
  const int f = t & 63, h = t >> 6;
  const float al = a[f], ar = a[64 + f];
  #pragma unroll
  for (int r = 0; r < 8; ++r) {
    float v = acc[r] * al;
    float u = acc[r] * ar;
    #pragma unroll
    for (int off = 32; off > 0; off >>= 1) {
      v += __shfl_xor(v, off);
      u += __shfl_xor(u, off);
    }
    if (f == 0) {
      el4[(r0 + r) * 4 + h] = v * LOG2E;                     // [i][h] (x LOG2E)
      float up = u * LOG2E;
      Qr[h * NN + (r0 + r)] = __builtin_amdgcn_exp2f(up);        // [h][j]
      Sr[h * NN + (r0 + r)] = __builtin_amdgcn_exp2f(0.2f * up); // [h][j]
    }
  }
}

// Kernel 0: pack adj to bits (ballot order: per 256-j window p, bit for j in
// word (j&3) at position (j>>2)) AND compute softmax denominators l[i,h];
// write premultiplied PL=P/l, RL=R/l. grid 1024 x 256; wave = 1 row.
__global__ __launch_bounds__(256, 4) void k0_pack(
    const float* __restrict__ adj, const float* __restrict__ el4,
    const float* __restrict__ Qr, const float* __restrict__ Sr,
    unsigned long long* __restrict__ adjB,
    float* __restrict__ PL, float* __restrict__ RL)
{
  const int t = threadIdx.x;
  const int w = t >> 6, l = t & 63;
  const int row = blockIdx.x * 4 + w;
  const float* arow = adj + (size_t)row * NN;

  float4 elv = *(const float4*)(el4 + row * 4);
  const float P[4] = { __builtin_amdgcn_exp2f(elv.x), __builtin_amdgcn_exp2f(elv.y),
                       __builtin_amdgcn_exp2f(elv.z), __builtin_amdgcn_exp2f(elv.w) };
  const float R[4] = { __builtin_amdgcn_exp2f(0.2f*elv.x), __builtin_amdgcn_exp2f(0.2f*elv.y),
                       __builtin_amdgcn_exp2f(0.2f*elv.z), __builtin_amdgcn_exp2f(0.2f*elv.w) };
  float lsum[4] = {0.f, 0.f, 0.f, 0.f};

  float4 av, qv0, qv1, qv2, qv3, sv0, sv1, sv2, sv3;
  av  = *(const float4*)(arow + l * 4);
  qv0 = *(const float4*)(Qr + 0 * NN + l * 4);
  qv1 = *(const float4*)(Qr + 1 * NN + l * 4);
  qv2 = *(const float4*)(Qr + 2 * NN + l * 4);
  qv3 = *(const float4*)(Qr + 3 * NN + l * 4);
  sv0 = *(const float4*)(Sr + 0 * NN + l * 4);
  sv1 = *(const float4*)(Sr + 1 * NN + l * 4);
  sv2 = *(const float4*)(Sr + 2 * NN + l * 4);
  sv3 = *(const float4*)(Sr + 3 * NN + l * 4);

  #pragma unroll 1
  for (int p = 0; p < 16; ++p) {
    const int nb = ((p < 15) ? (p + 1) * 256 : 0) + l * 4;
    float4 nav  = *(const float4*)(arow + nb);
    float4 nqv0 = *(const float4*)(Qr + 0 * NN + nb);
    float4 nqv1 = *(const float4*)(Qr + 1 * NN + nb);
    float4 nqv2 = *(const float4*)(Qr + 2 * NN + nb);
    float4 nqv3 = *(const float4*)(Qr + 3 * NN + nb);
    float4 nsv0 = *(const float4*)(Sr + 0 * NN + nb);
    float4 nsv1 = *(const float4*)(Sr + 1 * NN + nb);
    float4 nsv2 = *(const float4*)(Sr + 2 * NN + nb);
    float4 nsv3 = *(const float4*)(Sr + 3 * NN + nb);

    unsigned long long b0 = __ballot(av.x != 0.0f);
    unsigned long long b1 = __ballot(av.y != 0.0f);
    unsigned long long b2 = __ballot(av.z != 0.0f);
    unsigned long long b3 = __ballot(av.w != 0.0f);
    if (l == 0) {
      unsigned long long* dst = adjB + (size_t)row * 64 + p * 4;
      dst[0] = b0; dst[1] = b1; dst[2] = b2; dst[3] = b3;
    }
    #pragma unroll
    for (int h = 0; h < 4; ++h) {
      const float4 qv = (h==0)?qv0:(h==1)?qv1:(h==2)?qv2:qv3;
      const float4 sv = (h==0)?sv0:(h==1)?sv1:(h==2)?sv2:sv3;
      float m0 = fmaxf(P[h] * qv.x, R[h] * sv.x);
      float m1 = fmaxf(P[h] * qv.y, R[h] * sv.y);
      float m2 = fmaxf(P[h] * qv.z, R[h] * sv.z);
      float m3 = fmaxf(P[h] * qv.w, R[h] * sv.w);
      lsum[h] = fmaf(av.x, m0, lsum[h]);
      lsum[h] = fmaf(av.y, m1, lsum[h]);
      lsum[h] = fmaf(av.z, m2, lsum[h]);
      lsum[h] = fmaf(av.w, m3, lsum[h]);
    }
    av = nav;
    qv0 = nqv0; qv1 = nqv1; qv2 = nqv2; qv3 = nqv3;
    sv0 = nsv0; sv1 = nsv1; sv2 = nsv2; sv3 = nsv3;
  }

  #pragma unroll
  for (int h = 0; h < 4; ++h) {
    float v = lsum[h];
    #pragma unroll
    for (int off = 32; off > 0; off >>= 1) v += __shfl_xor(v, off);
    lsum[h] = v;
  }
  if (l < 4) {
    float li = 1.0f / lsum[l];    // l > 0: diagonal of adj is 1
    PL[row * 4 + l] = P[l] * li;
    RL[row * 4 + l] = R[l] * li;
  }
}

// Kernel 2: masked-softmax-weighted PV via MFMA, heads folded.
// grid (256 i-tiles of 16 rows, 4 splits of 1024 j), block 256 = 4 waves.
// All 4 waves compute the SAME 16x64 output tile over different 256-j
// windows (sw = split*4 + w); LDS merge, wave 0 does the atomics (4/cell).
// lane: m = l&15 (row), q = l>>4 (k-quad).
__global__ __launch_bounds__(256, 4) void k2_attn(
    const unsigned long long* __restrict__ adjB, const unsigned short* __restrict__ Vf,
    const float* __restrict__ PL, const float* __restrict__ RL,
    const float* __restrict__ Qr, const float* __restrict__ Sr,
    float* __restrict__ out)
{
  __shared__ float qs[8192];           // 32KB: [w][h][jc][q][16] {Q[8],S[8]}
  const int t = threadIdx.x;
  const int w = t >> 6, l = t & 63;
  const int m = l & 15, q = l >> 4;
  const int i0 = blockIdx.x * 16;
  const int sw = blockIdx.y * 4 + w;   // this wave's 256-j window (0..15)
  const int i = i0 + m;
  const int jwin = sw * 256;

  // wave-private staging: no barrier needed before use
  {
    const int jc = l >> 3, qq = (l >> 1) & 3, hp = (l & 1) * 4;
    #pragma unroll
    for (int h = 0; h < 4; ++h) {
      float4 qv = *(const float4*)(Qr + h * NN + jwin + l * 4);
      float4 sv = *(const float4*)(Sr + h * NN + jwin + l * 4);
      float* cell = qs + (((w * 4 + h) * 8 + jc) * 4 + qq) * 16;
      *(float4*)(cell + hp) = qv;
      *(float4*)(cell + 8 + hp) = sv;
    }
  }

  float4 pl4 = *(const float4*)(PL + i * 4);
  float4 rl4 = *(const float4*)(RL + i * 4);
  const float Pl[4] = {pl4.x, pl4.y, pl4.z, pl4.w};
  const float Rl[4] = {rl4.x, rl4.y, rl4.z, rl4.w};

  // window mask: 4 x 64-bit ballot words
  const unsigned long long* bp = adjB + (size_t)i * 64 + sw * 4;
  unsigned long long b0 = bp[0], b1 = bp[1], b2 = bp[2], b3 = bp[3];

  f4v acc[4];
  #pragma unroll
  for (int nf = 0; nf < 4; ++nf) acc[nf] = (f4v){0.f, 0.f, 0.f, 0.f};

  const s8v* vfp = (const s8v*)Vf;
  s8v Bc[4];
  #pragma unroll
  for (int nf = 0; nf < 4; ++nf)
    Bc[nf] = vfp[(size_t)((0 * 128 + sw * 8 + 0) * 4 + nf) * 64 + l];

  #pragma unroll 1
  for (int jc = 0; jc < 8; ++jc) {
    const unsigned sh = jc * 8 + q * 2;
    const unsigned t0 = (unsigned)(b0 >> sh) & 3u;
    const unsigned t1 = (unsigned)(b1 >> sh) & 3u;
    const unsigned t2 = (unsigned)(b2 >> sh) & 3u;
    const unsigned t3 = (unsigned)(b3 >> sh) & 3u;
    float bitf[8];
    bitf[0] = (float)(t0 & 1u); bitf[4] = (float)(t0 >> 1);
    bitf[1] = (float)(t1 & 1u); bitf[5] = (float)(t1 >> 1);
    bitf[2] = (float)(t2 & 1u); bitf[6] = (float)(t2 >> 1);
    bitf[3] = (float)(t3 & 1u); bitf[7] = (float)(t3 >> 1);

    #pragma unroll
    for (int h = 0; h < 4; ++h) {
      const int hn = (h < 3) ? h + 1 : 0;
      const int jcn = (h < 3) ? jc : jc + 1;
      s8v Bn[4];
      #pragma unroll
      for (int nf = 0; nf < 4; ++nf)
        Bn[nf] = vfp[(size_t)((hn * 128 + sw * 8 + jcn) * 4 + nf) * 64 + l];

      const float* cell = qs + (((w * 4 + h) * 8 + jc) * 4 + q) * 16;
      float4 q0  = *(const float4*)(cell);
      float4 q1  = *(const float4*)(cell + 4);
      float4 sv0 = *(const float4*)(cell + 8);
      float4 sv1 = *(const float4*)(cell + 12);
      const float Ph = Pl[h], Rh = Rl[h];
      float s0 = bitf[0] * fmaxf(Ph * q0.x, Rh * sv0.x);
      float s1 = bitf[1] * fmaxf(Ph * q0.y, Rh * sv0.y);
      float s2 = bitf[2] * fmaxf(Ph * q0.z, Rh * sv0.z);
      float s3 = bitf[3] * fmaxf(Ph * q0.w, Rh * sv0.w);
      float s4 = bitf[4] * fmaxf(Ph * q1.x, Rh * sv1.x);
      float s5 = bitf[5] * fmaxf(Ph * q1.y, Rh * sv1.y);
      float s6 = bitf[6] * fmaxf(Ph * q1.z, Rh * sv1.z);
      float s7 = bitf[7] * fmaxf(Ph * q1.w, Rh * sv1.w);
      union { unsigned u[4]; s8v v; } A;   // A-frag: row m, k = q*8+idx
      A.u[0] = pack2_rne(s0, s1);
      A.u[1] = pack2_rne(s2, s3);
      A.u[2] = pack2_rne(s4, s5);
      A.u[3] = pack2_rne(s6, s7);
      #pragma unroll
      for (int nf = 0; nf < 4; ++nf)
        acc[nf] = __builtin_amdgcn_mfma_f32_16x16x32_bf16(A.v, Bc[nf], acc[nf], 0, 0, 0);
      #pragma unroll
      for (int nf = 0; nf < 4; ++nf) Bc[nf] = Bn[nf];
    }
  }

  // merge 4 waves' tiles in LDS (reuse qs; f4v stride 20 -> conflict-free)
  // wave w>0 stores at float offset (w-1)*1280 + l*20; wave 0 reads 0/1280/2560.
  __syncthreads();                     // all qs reads done
  if (w > 0) {
    float* dst = qs + ((w - 1) * 64 + l) * 20;
    #pragma unroll
    for (int nf = 0; nf < 4; ++nf)
      *(f4v*)(dst + nf * 4) = acc[nf];
  }
  __syncthreads();
  if (w == 0) {
    const float* src = qs + l * 20;
    #pragma unroll
    for (int nf = 0; nf < 4; ++nf) {
      f4v s = acc[nf];
      s += *(const f4v*)(src +    0 + nf * 4);   // wave1 (stored at offset 0)
      s += *(const f4v*)(src + 1280 + nf * 4);   // wave2
      s += *(const f4v*)(src + 2560 + nf * 4);   // wave3
      #pragma unroll
      for (int r = 0; r < 4; ++r) {
        int row = i0 + q * 4 + r;
        int col = nf * 16 + m;
        atomicAdd(&out[row * 64 + col], 0.25f * s[r]);
      }
    }
  }
}

extern "C" void kernel_launch(void* const* d_in, const int* in_sizes, int n_in,
                              void* d_out, int out_size, void* d_ws, size_t ws_size,
                              hipStream_t stream) {
  const float* x   = (const float*)d_in[0];   // (4096, 256)
  const float* adj = (const float*)d_in[1];   // (4096, 4096)
  const float* W   = (const float*)d_in[2];   // (256, 256)
  const float* a   = (const float*)d_in[3];   // (128, 1)
  float* out = (float*)d_out;                 // (4096, 64)

  char* ws = (char*)d_ws;
  unsigned short* Vf = (unsigned short*)ws;                  // 2 MB  bf16 fragment-ordered
  float* el4 = (float*)(ws + (2u << 20));                    // 64 KB [4096][4]
  float* Qr  = (float*)(ws + (2u << 20) + (64u << 10));      // 64 KB [4][4096]
  float* Sr  = (float*)(ws + (2u << 20) + (128u << 10));     // 64 KB [4][4096]
  float* PLp = (float*)(ws + (2u << 20) + (192u << 10));     // 64 KB [4096][4]
  float* RLp = (float*)(ws + (2u << 20) + (256u << 10));     // 64 KB [4096][4]
  unsigned long long* adjB = (unsigned long long*)(ws + (2u << 20) + (320u << 10)); // 2 MB bits

  hipMemsetAsync(out, 0, (size_t)out_size * sizeof(float), stream);
  k1_proj<<<512, 256, 0, stream>>>(x, W, a, Vf, el4, Qr, Sr);
  k0_pack<<<1024, 256, 0, stream>>>(adj, el4, Qr, Sr, adjB, PLp, RLp);
  k2_attn<<<dim3(256, 4), 256, 0, stream>>>(adjB, Vf, PLp, RLp, Qr, Sr, out);
}

// Round 10
// 170.025 us; speedup vs baseline: 1.4046x; 1.0252x over previous
//
#include <hip/hip_runtime.h>
#include <hip/hip_bf16.h>

#define NN 4096
#define LOG2E 1.44269504088896340736f

typedef __attribute__((ext_vector_type(8))) short s8v;   // 8 x bf16
typedef __attribute__((ext_vector_type(4))) float f4v;   // mfma accumulator

__device__ __forceinline__ unsigned fu(float x){ union{float f;unsigned u;}z; z.f=x; return z.u; }
__device__ __forceinline__ unsigned short f2bf_rne(float x){
  unsigned u = fu(x);
  u += 0x7fffu + ((u >> 16) & 1u);
  return (unsigned short)(u >> 16);
}
__device__ __forceinline__ unsigned pack2_rne(float a, float b){
  return (unsigned)f2bf_rne(a) | ((unsigned)f2bf_rne(b) << 16);
}

// Kernel 1: h = x@W (fp32), write Vf in MFMA-fragment order (bf16),
// el' (x LOG2E) and factorized exponentials Qr=exp2(er'), Sr=exp2(0.2*er').
__global__ __launch_bounds__(256) void k1_proj(
    const float* __restrict__ x, const float* __restrict__ W,
    const float* __restrict__ a, unsigned short* __restrict__ Vf,
    float* __restrict__ el4, float* __restrict__ Qr, float* __restrict__ Sr)
{
  __shared__ float4 xs[512];           // 8 rows x 256 cols fp32
  const int t = threadIdx.x;
  const int r0 = blockIdx.x * 8;
  const float4* xg = (const float4*)(x + (size_t)r0 * 256);
  xs[t] = xg[t];
  xs[t + 256] = xg[t + 256];
  __syncthreads();

  float acc[8] = {0.f,0.f,0.f,0.f,0.f,0.f,0.f,0.f};
  const float* Wp = W + t;             // column c = t
  float w0 = Wp[0], w1 = Wp[256], w2 = Wp[512], w3 = Wp[768];
  #pragma unroll 1
  for (int k4 = 0; k4 < 64; ++k4) {
    const int kn = (k4 + 1) & 63;
    float nw0 = Wp[kn*1024 +   0];
    float nw1 = Wp[kn*1024 + 256];
    float nw2 = Wp[kn*1024 + 512];
    float nw3 = Wp[kn*1024 + 768];
    #pragma unroll
    for (int r = 0; r < 8; ++r) {
      float4 xv = xs[r*64 + k4];       // broadcast LDS read
      acc[r] = fmaf(xv.x, w0, acc[r]);
      acc[r] = fmaf(xv.y, w1, acc[r]);
      acc[r] = fmaf(xv.z, w2, acc[r]);
      acc[r] = fmaf(xv.w, w3, acc[r]);
    }
    w0 = nw0; w1 = nw1; w2 = nw2; w3 = nw3;
  }

  // Vf write: thread t holds V[r0..r0+7][c=t] -> exactly one fragment chunk
  union { unsigned u[4]; s8v v; } pk;
  #pragma unroll
  for (int p = 0; p < 4; ++p)
    pk.u[p] = pack2_rne(acc[2*p], acc[2*p+1]);
  {
    const int hh = t >> 6, nf = (t >> 4) & 3, mm = t & 15;
    const int jblk = r0 >> 5, qq = (r0 >> 3) & 3;
    const size_t chunk = (size_t)(((hh * 128 + jblk) * 4 + nf) * 64 + qq * 16 + mm);
    *(s8v*)(Vf + chunk * 8) = pk.v;
  }

  // el/er: wave w == head h; lane f = t&63
  const int f = t & 63, h = t >> 6;
  const float al = a[f], ar = a[64 + f];
  #pragma unroll
  for (int r = 0; r < 8; ++r) {
    float v = acc[r] * al;
    float u = acc[r] * ar;
    #pragma unroll
    for (int off = 32; off > 0; off >>= 1) {
      v += __shfl_xor(v, off);
      u += __shfl_xor(u, off);
    }
    if (f == 0) {
      el4[(r0 + r) * 4 + h] = v * LOG2E;                     // [i][h] (x LOG2E)
      float up = u * LOG2E;
      Qr[h * NN + (r0 + r)] = __builtin_amdgcn_exp2f(up);        // [h][j]
      Sr[h * NN + (r0 + r)] = __builtin_amdgcn_exp2f(0.2f * up); // [h][j]
    }
  }
}

// Kernel 0: pack adj to bits AND accumulate softmax denominators lsum[i][h].
// grid (1024 row-groups, 16 windows), block 256 = 4 waves; wave = 1 row,
// all 4 waves share window p (Q/S staged once in LDS -> kills the 1GB L2
// redundancy of the row-serial version). Ballot order: per 256-j window,
// bit for j in word (j&3) at position (j>>2). lsum via 4 atomics/wave.
__global__ __launch_bounds__(256, 8) void k0_pack(
    const float* __restrict__ adj, const float* __restrict__ el4,
    const float* __restrict__ Qr, const float* __restrict__ Sr,
    unsigned long long* __restrict__ adjB, float* __restrict__ lsum)
{
  __shared__ float qsh[2048];          // 8KB: Q[h][256] then S[h][256]
  const int t = threadIdx.x;
  const int w = t >> 6, l = t & 63;
  const int p = blockIdx.y;
  const int row = blockIdx.x * 4 + w;
  const int jwin = p * 256;

  // cooperative stage: thread t = (h = t>>6, lane l) loads 4 j's of Q and S
  {
    const int h = t >> 6;
    float4 qv = *(const float4*)(Qr + h * NN + jwin + l * 4);
    float4 sv = *(const float4*)(Sr + h * NN + jwin + l * 4);
    *(float4*)(qsh + h * 256 + l * 4) = qv;
    *(float4*)(qsh + 1024 + h * 256 + l * 4) = sv;
  }

  // wave's adj quad (coalesced 1KB per wave)
  const float4 av = *(const float4*)(adj + (size_t)row * NN + jwin + l * 4);

  // pack bits
  unsigned long long b0 = __ballot(av.x != 0.0f);
  unsigned long long b1 = __ballot(av.y != 0.0f);
  unsigned long long b2 = __ballot(av.z != 0.0f);
  unsigned long long b3 = __ballot(av.w != 0.0f);
  if (l == 0) {
    unsigned long long* dst = adjB + (size_t)row * 64 + p * 4;
    dst[0] = b0; dst[1] = b1; dst[2] = b2; dst[3] = b3;
  }

  // P,R for this row (wave-uniform redundant compute, cheap)
  float4 elv = *(const float4*)(el4 + row * 4);
  const float P[4] = { __builtin_amdgcn_exp2f(elv.x), __builtin_amdgcn_exp2f(elv.y),
                       __builtin_amdgcn_exp2f(elv.z), __builtin_amdgcn_exp2f(elv.w) };
  const float R[4] = { __builtin_amdgcn_exp2f(0.2f*elv.x), __builtin_amdgcn_exp2f(0.2f*elv.y),
                       __builtin_amdgcn_exp2f(0.2f*elv.z), __builtin_amdgcn_exp2f(0.2f*elv.w) };

  __syncthreads();

  float ls[4];
  #pragma unroll
  for (int h = 0; h < 4; ++h) {
    float4 qv = *(const float4*)(qsh + h * 256 + l * 4);
    float4 sv = *(const float4*)(qsh + 1024 + h * 256 + l * 4);
    float s;
    s  = av.x * fmaxf(P[h] * qv.x, R[h] * sv.x);
    s  = fmaf(av.y, fmaxf(P[h] * qv.y, R[h] * sv.y), s);
    s  = fmaf(av.z, fmaxf(P[h] * qv.z, R[h] * sv.z), s);
    s  = fmaf(av.w, fmaxf(P[h] * qv.w, R[h] * sv.w), s);
    ls[h] = s;
  }
  #pragma unroll
  for (int h = 0; h < 4; ++h) {
    float v = ls[h];
    #pragma unroll
    for (int off = 32; off > 0; off >>= 1) v += __shfl_xor(v, off);
    ls[h] = v;
  }
  if (l == 0) {
    #pragma unroll
    for (int h = 0; h < 4; ++h)
      atomicAdd(&lsum[row * 4 + h], ls[h]);
  }
}

// Kernel 2: masked-softmax-weighted PV via MFMA, heads folded.
// grid (256 i-tiles of 16 rows, 4 splits of 1024 j), block 256 = 4 waves.
// All 4 waves compute the SAME 16x64 output tile over different 256-j
// windows (sw = split*4 + w); LDS merge, wave 0 does the atomics (4/cell).
// PL/RL computed inline from el4 + lsum. lane: m = l&15, q = l>>4.
__global__ __launch_bounds__(256, 4) void k2_attn(
    const unsigned long long* __restrict__ adjB, const unsigned short* __restrict__ Vf,
    const float* __restrict__ el4, const float* __restrict__ lsum,
    const float* __restrict__ Qr, const float* __restrict__ Sr,
    float* __restrict__ out)
{
  __shared__ float qs[8192];           // 32KB: [w][h][jc][q][16] {Q[8],S[8]}
  const int t = threadIdx.x;
  const int w = t >> 6, l = t & 63;
  const int m = l & 15, q = l >> 4;
  const int i0 = blockIdx.x * 16;
  const int sw = blockIdx.y * 4 + w;   // this wave's 256-j window (0..15)
  const int i = i0 + m;
  const int jwin = sw * 256;

  // wave-private staging: no barrier needed before use
  {
    const int jc = l >> 3, qq = (l >> 1) & 3, hp = (l & 1) * 4;
    #pragma unroll
    for (int h = 0; h < 4; ++h) {
      float4 qv = *(const float4*)(Qr + h * NN + jwin + l * 4);
      float4 sv = *(const float4*)(Sr + h * NN + jwin + l * 4);
      float* cell = qs + (((w * 4 + h) * 8 + jc) * 4 + qq) * 16;
      *(float4*)(cell + hp) = qv;
      *(float4*)(cell + 8 + hp) = sv;
    }
  }

  // inline PL/RL: P/l, R/l for row i
  float4 elv = *(const float4*)(el4 + i * 4);
  float4 ls4 = *(const float4*)(lsum + i * 4);
  float Pl[4], Rl[4];
  {
    const float el_[4] = {elv.x, elv.y, elv.z, elv.w};
    const float lv_[4] = {ls4.x, ls4.y, ls4.z, ls4.w};
    #pragma unroll
    for (int h = 0; h < 4; ++h) {
      const float inv = 1.0f / lv_[h];   // lv > 0: diagonal of adj is 1
      Pl[h] = __builtin_amdgcn_exp2f(el_[h]) * inv;
      Rl[h] = __builtin_amdgcn_exp2f(0.2f * el_[h]) * inv;
    }
  }

  // window mask: 4 x 64-bit ballot words
  const unsigned long long* bp = adjB + (size_t)i * 64 + sw * 4;
  unsigned long long b0 = bp[0], b1 = bp[1], b2 = bp[2], b3 = bp[3];

  f4v acc[4];
  #pragma unroll
  for (int nf = 0; nf < 4; ++nf) acc[nf] = (f4v){0.f, 0.f, 0.f, 0.f};

  const s8v* vfp = (const s8v*)Vf;
  s8v Bc[4];
  #pragma unroll
  for (int nf = 0; nf < 4; ++nf)
    Bc[nf] = vfp[(size_t)((0 * 128 + sw * 8 + 0) * 4 + nf) * 64 + l];

  #pragma unroll 1
  for (int jc = 0; jc < 8; ++jc) {
    const unsigned sh = jc * 8 + q * 2;
    const unsigned t0 = (unsigned)(b0 >> sh) & 3u;
    const unsigned t1 = (unsigned)(b1 >> sh) & 3u;
    const unsigned t2 = (unsigned)(b2 >> sh) & 3u;
    const unsigned t3 = (unsigned)(b3 >> sh) & 3u;
    float bitf[8];
    bitf[0] = (float)(t0 & 1u); bitf[4] = (float)(t0 >> 1);
    bitf[1] = (float)(t1 & 1u); bitf[5] = (float)(t1 >> 1);
    bitf[2] = (float)(t2 & 1u); bitf[6] = (float)(t2 >> 1);
    bitf[3] = (float)(t3 & 1u); bitf[7] = (float)(t3 >> 1);

    #pragma unroll
    for (int h = 0; h < 4; ++h) {
      const int hn = (h < 3) ? h + 1 : 0;
      const int jcn = (h < 3) ? jc : jc + 1;
      s8v Bn[4];
      #pragma unroll
      for (int nf = 0; nf < 4; ++nf)
        Bn[nf] = vfp[(size_t)((hn * 128 + sw * 8 + jcn) * 4 + nf) * 64 + l];

      const float* cell = qs + (((w * 4 + h) * 8 + jc) * 4 + q) * 16;
      float4 q0  = *(const float4*)(cell);
      float4 q1  = *(const float4*)(cell + 4);
      float4 sv0 = *(const float4*)(cell + 8);
      float4 sv1 = *(const float4*)(cell + 12);
      const float Ph = Pl[h], Rh = Rl[h];
      float s0 = bitf[0] * fmaxf(Ph * q0.x, Rh * sv0.x);
      float s1 = bitf[1] * fmaxf(Ph * q0.y, Rh * sv0.y);
      float s2 = bitf[2] * fmaxf(Ph * q0.z, Rh * sv0.z);
      float s3 = bitf[3] * fmaxf(Ph * q0.w, Rh * sv0.w);
      float s4 = bitf[4] * fmaxf(Ph * q1.x, Rh * sv1.x);
      float s5 = bitf[5] * fmaxf(Ph * q1.y, Rh * sv1.y);
      float s6 = bitf[6] * fmaxf(Ph * q1.z, Rh * sv1.z);
      float s7 = bitf[7] * fmaxf(Ph * q1.w, Rh * sv1.w);
      union { unsigned u[4]; s8v v; } A;   // A-frag: row m, k = q*8+idx
      A.u[0] = pack2_rne(s0, s1);
      A.u[1] = pack2_rne(s2, s3);
      A.u[2] = pack2_rne(s4, s5);
      A.u[3] = pack2_rne(s6, s7);
      #pragma unroll
      for (int nf = 0; nf < 4; ++nf)
        acc[nf] = __builtin_amdgcn_mfma_f32_16x16x32_bf16(A.v, Bc[nf], acc[nf], 0, 0, 0);
      #pragma unroll
      for (int nf = 0; nf < 4; ++nf) Bc[nf] = Bn[nf];
    }
  }

  // merge 4 waves' tiles in LDS (reuse qs; f4v stride 20 -> conflict-free)
  __syncthreads();                     // all qs reads done
  if (w > 0) {
    float* dst = qs + ((w - 1) * 64 + l) * 20;
    #pragma unroll
    for (int nf = 0; nf < 4; ++nf)
      *(f4v*)(dst + nf * 4) = acc[nf];
  }
  __syncthreads();
  if (w == 0) {
    const float* src = qs + l * 20;
    #pragma unroll
    for (int nf = 0; nf < 4; ++nf) {
      f4v s = acc[nf];
      s += *(const f4v*)(src +    0 + nf * 4);   // wave1
      s += *(const f4v*)(src + 1280 + nf * 4);   // wave2
      s += *(const f4v*)(src + 2560 + nf * 4);   // wave3
      #pragma unroll
      for (int r = 0; r < 4; ++r) {
        int row = i0 + q * 4 + r;
        int col = nf * 16 + m;
        atomicAdd(&out[row * 64 + col], 0.25f * s[r]);
      }
    }
  }
}

extern "C" void kernel_launch(void* const* d_in, const int* in_sizes, int n_in,
                              void* d_out, int out_size, void* d_ws, size_t ws_size,
                              hipStream_t stream) {
  const float* x   = (const float*)d_in[0];   // (4096, 256)
  const float* adj = (const float*)d_in[1];   // (4096, 4096)
  const float* W   = (const float*)d_in[2];   // (256, 256)
  const float* a   = (const float*)d_in[3];   // (128, 1)
  float* out = (float*)d_out;                 // (4096, 64)

  char* ws = (char*)d_ws;
  unsigned short* Vf = (unsigned short*)ws;                  // 2 MB  bf16 fragment-ordered
  float* el4 = (float*)(ws + (2u << 20));                    // 64 KB [4096][4]
  float* Qr  = (float*)(ws + (2u << 20) + (64u << 10));      // 64 KB [4][4096]
  float* Sr  = (float*)(ws + (2u << 20) + (128u << 10));     // 64 KB [4][4096]
  float* lsum= (float*)(ws + (2u << 20) + (192u << 10));     // 64 KB [4096][4]
  unsigned long long* adjB = (unsigned long long*)(ws + (2u << 20) + (256u << 10)); // 2 MB bits

  hipMemsetAsync(out, 0, (size_t)out_size * sizeof(float), stream);
  hipMemsetAsync(lsum, 0, NN * 4 * sizeof(float), stream);
  k1_proj<<<512, 256, 0, stream>>>(x, W, a, Vf, el4, Qr, Sr);
  k0_pack<<<dim3(1024, 16), 256, 0, stream>>>(adj, el4, Qr, Sr, adjB, lsum);
  k2_attn<<<dim3(256, 4), 256, 0, stream>>>(adjB, Vf, el4, lsum, Qr, Sr, out);
}

// Round 11
// 159.638 us; speedup vs baseline: 1.4959x; 1.0651x over previous
//
#include <hip/hip_runtime.h>
#include <hip/hip_bf16.h>

#define NN 4096
#define LOG2E 1.44269504088896340736f

typedef __attribute__((ext_vector_type(8))) short s8v;   // 8 x bf16
typedef __attribute__((ext_vector_type(4))) float f4v;   // mfma accumulator

__device__ __forceinline__ unsigned fu(float x){ union{float f;unsigned u;}z; z.f=x; return z.u; }
__device__ __forceinline__ unsigned short f2bf_rne(float x){
  unsigned u = fu(x);
  u += 0x7fffu + ((u >> 16) & 1u);
  return (unsigned short)(u >> 16);
}
__device__ __forceinline__ unsigned pack2_rne(float a, float b){
  return (unsigned)f2bf_rne(a) | ((unsigned)f2bf_rne(b) << 16);
}

// Kernel 1: h = x@W (fp32), write Vf in MFMA-fragment order (bf16),
// el' (x LOG2E) and factorized exponentials Qr=exp2(er'), Sr=exp2(0.2*er').
// W loads: depth-2 software pipeline.
__global__ __launch_bounds__(256) void k1_proj(
    const float* __restrict__ x, const float* __restrict__ W,
    const float* __restrict__ a, unsigned short* __restrict__ Vf,
    float* __restrict__ el4, float* __restrict__ Qr, float* __restrict__ Sr)
{
  __shared__ float4 xs[512];           // 8 rows x 256 cols fp32
  const int t = threadIdx.x;
  const int r0 = blockIdx.x * 8;
  const float4* xg = (const float4*)(x + (size_t)r0 * 256);
  xs[t] = xg[t];
  xs[t + 256] = xg[t + 256];
  __syncthreads();

  float acc[8] = {0.f,0.f,0.f,0.f,0.f,0.f,0.f,0.f};
  const float* Wp = W + t;             // column c = t
  float wa0 = Wp[0],    wa1 = Wp[256],  wa2 = Wp[512],  wa3 = Wp[768];
  float wb0 = Wp[1024], wb1 = Wp[1280], wb2 = Wp[1536], wb3 = Wp[1792];
  #pragma unroll 1
  for (int k4 = 0; k4 < 64; ++k4) {
    const int kn = (k4 + 2) & 63;      // depth-2 prefetch, wrap stays in-bounds
    float nw0 = Wp[kn*1024 +   0];
    float nw1 = Wp[kn*1024 + 256];
    float nw2 = Wp[kn*1024 + 512];
    float nw3 = Wp[kn*1024 + 768];
    #pragma unroll
    for (int r = 0; r < 8; ++r) {
      float4 xv = xs[r*64 + k4];       // broadcast LDS read
      acc[r] = fmaf(xv.x, wa0, acc[r]);
      acc[r] = fmaf(xv.y, wa1, acc[r]);
      acc[r] = fmaf(xv.z, wa2, acc[r]);
      acc[r] = fmaf(xv.w, wa3, acc[r]);
    }
    wa0 = wb0; wa1 = wb1; wa2 = wb2; wa3 = wb3;
    wb0 = nw0; wb1 = nw1; wb2 = nw2; wb3 = nw3;
  }

  // Vf write: thread t holds V[r0..r0+7][c=t] -> exactly one fragment chunk
  union { unsigned u[4]; s8v v; } pk;
  #pragma unroll
  for (int p = 0; p < 4; ++p)
    pk.u[p] = pack2_rne(acc[2*p], acc[2*p+1]);
  {
    const int hh = t >> 6, nf = (t >> 4) & 3, mm = t & 15;
    const int jblk = r0 >> 5, qq = (r0 >> 3) & 3;
    const size_t chunk = (size_t)(((hh * 128 + jblk) * 4 + nf) * 64 + qq * 16 + mm);
    *(s8v*)(Vf + chunk * 8) = pk.v;
  }

  // el/er: wave w == head h; lane f = t&63
  const int f = t & 63, h = t >> 6;
  const float al = a[f], ar = a[64 + f];
  #pragma unroll
  for (int r = 0; r < 8; ++r) {
    float v = acc[r] * al;
    float u = acc[r] * ar;
    #pragma unroll
    for (int off = 32; off > 0; off >>= 1) {
      v += __shfl_xor(v, off);
      u += __shfl_xor(u, off);
    }
    if (f == 0) {
      el4[(r0 + r) * 4 + h] = v * LOG2E;                     // [i][h] (x LOG2E)
      float up = u * LOG2E;
      Qr[h * NN + (r0 + r)] = __builtin_amdgcn_exp2f(up);        // [h][j]
      Sr[h * NN + (r0 + r)] = __builtin_amdgcn_exp2f(0.2f * up); // [h][j]
    }
  }
}

// Kernel 0: pack adj to bits AND softmax-denominator partials, 4 windows per
// block. grid (1024 row-groups, 4 window-groups), block 256 = 4 waves;
// wave = 1 row x 4 windows -> 4 independent adj float4 HBM loads in flight.
// Q/S for the 4 windows staged once in LDS (32 KB). One reduction per wave.
// Ballot order per 256-j window: bit for j in word (j&3) at position (j>>2).
// lsumP[p4][row][h] written with plain stores (no atomics, no memset).
__global__ __launch_bounds__(256, 4) void k0_pack(
    const float* __restrict__ adj, const float* __restrict__ el4,
    const float* __restrict__ Qr, const float* __restrict__ Sr,
    unsigned long long* __restrict__ adjB, float* __restrict__ lsumP)
{
  __shared__ float qsh[8192];          // 32KB: [k(4)][{Q,S}][h(4)][256]
  const int t = threadIdx.x;
  const int w = t >> 6, l = t & 63;
  const int row = blockIdx.x * 4 + w;
  const int p4 = blockIdx.y;
  const int jbase = p4 * 1024;

  // issue the 4 HBM adj loads first (deep MLP)
  const float* arow = adj + (size_t)row * NN + jbase + l * 4;
  float4 av0 = *(const float4*)(arow);
  float4 av1 = *(const float4*)(arow + 256);
  float4 av2 = *(const float4*)(arow + 512);
  float4 av3 = *(const float4*)(arow + 768);

  // cooperative stage: thread (h = t>>6, lane l), 4 windows x {Q,S}
  {
    const int h = t >> 6;
    #pragma unroll
    for (int k = 0; k < 4; ++k) {
      float4 qv = *(const float4*)(Qr + h * NN + jbase + k * 256 + l * 4);
      float4 sv = *(const float4*)(Sr + h * NN + jbase + k * 256 + l * 4);
      *(float4*)(qsh + ((k * 2 + 0) * 4 + h) * 256 + l * 4) = qv;
      *(float4*)(qsh + ((k * 2 + 1) * 4 + h) * 256 + l * 4) = sv;
    }
  }

  // pack bits (window = p4*4 + k)
  {
    unsigned long long* dst = adjB + (size_t)row * 64 + p4 * 16;
    const float4 avs[4] = {av0, av1, av2, av3};
    #pragma unroll
    for (int k = 0; k < 4; ++k) {
      unsigned long long b0 = __ballot(avs[k].x != 0.0f);
      unsigned long long b1 = __ballot(avs[k].y != 0.0f);
      unsigned long long b2 = __ballot(avs[k].z != 0.0f);
      unsigned long long b3 = __ballot(avs[k].w != 0.0f);
      if (l == 0) {
        dst[k * 4 + 0] = b0; dst[k * 4 + 1] = b1;
        dst[k * 4 + 2] = b2; dst[k * 4 + 3] = b3;
      }
    }
  }

  // P,R for this row (wave-uniform)
  float4 elv = *(const float4*)(el4 + row * 4);
  const float P[4] = { __builtin_amdgcn_exp2f(elv.x), __builtin_amdgcn_exp2f(elv.y),
                       __builtin_amdgcn_exp2f(elv.z), __builtin_amdgcn_exp2f(elv.w) };
  const float R[4] = { __builtin_amdgcn_exp2f(0.2f*elv.x), __builtin_amdgcn_exp2f(0.2f*elv.y),
                       __builtin_amdgcn_exp2f(0.2f*elv.z), __builtin_amdgcn_exp2f(0.2f*elv.w) };

  __syncthreads();

  float ls[4] = {0.f, 0.f, 0.f, 0.f};
  {
    const float4 avs[4] = {av0, av1, av2, av3};
    #pragma unroll
    for (int k = 0; k < 4; ++k) {
      const float4 av = avs[k];
      #pragma unroll
      for (int h = 0; h < 4; ++h) {
        float4 qv = *(const float4*)(qsh + ((k * 2 + 0) * 4 + h) * 256 + l * 4);
        float4 sv = *(const float4*)(qsh + ((k * 2 + 1) * 4 + h) * 256 + l * 4);
        float s;
        s = av.x * fmaxf(P[h] * qv.x, R[h] * sv.x);
        s = fmaf(av.y, fmaxf(P[h] * qv.y, R[h] * sv.y), s);
        s = fmaf(av.z, fmaxf(P[h] * qv.z, R[h] * sv.z), s);
        s = fmaf(av.w, fmaxf(P[h] * qv.w, R[h] * sv.w), s);
        ls[h] += s;
      }
    }
  }
  #pragma unroll
  for (int h = 0; h < 4; ++h) {
    float v = ls[h];
    #pragma unroll
    for (int off = 32; off > 0; off >>= 1) v += __shfl_xor(v, off);
    ls[h] = v;
  }
  if (l == 0)
    *(float4*)(lsumP + ((size_t)p4 * NN + row) * 4) = make_float4(ls[0], ls[1], ls[2], ls[3]);
}

// Kernel 2: masked-softmax-weighted PV via MFMA, heads folded.
// grid (256 i-tiles of 16 rows, 4 splits of 1024 j), block 256 = 4 waves.
// All 4 waves compute the SAME 16x64 output tile over different 256-j
// windows (sw = split*4 + w); LDS merge, wave 0 does the atomics (4/cell).
// l = sum of 4 lsumP partials; PL/RL inline. lane: m = l&15, q = l>>4.
__global__ __launch_bounds__(256, 4) void k2_attn(
    const unsigned long long* __restrict__ adjB, const unsigned short* __restrict__ Vf,
    const float* __restrict__ el4, const float* __restrict__ lsumP,
    const float* __restrict__ Qr, const float* __restrict__ Sr,
    float* __restrict__ out)
{
  __shared__ float qs[8192];           // 32KB: [w][h][jc][q][16] {Q[8],S[8]}
  const int t = threadIdx.x;
  const int w = t >> 6, l = t & 63;
  const int m = l & 15, q = l >> 4;
  const int i0 = blockIdx.x * 16;
  const int sw = blockIdx.y * 4 + w;   // this wave's 256-j window (0..15)
  const int i = i0 + m;
  const int jwin = sw * 256;

  // wave-private staging: no barrier needed before use
  {
    const int jc = l >> 3, qq = (l >> 1) & 3, hp = (l & 1) * 4;
    #pragma unroll
    for (int h = 0; h < 4; ++h) {
      float4 qv = *(const float4*)(Qr + h * NN + jwin + l * 4);
      float4 sv = *(const float4*)(Sr + h * NN + jwin + l * 4);
      float* cell = qs + (((w * 4 + h) * 8 + jc) * 4 + qq) * 16;
      *(float4*)(cell + hp) = qv;
      *(float4*)(cell + 8 + hp) = sv;
    }
  }

  // l[i][h] = sum of 4 partials; then PL/RL inline
  float4 elv = *(const float4*)(el4 + i * 4);
  float lx = 0.f, ly = 0.f, lz = 0.f, lw = 0.f;
  #pragma unroll
  for (int p = 0; p < 4; ++p) {
    float4 v = *(const float4*)(lsumP + ((size_t)p * NN + i) * 4);
    lx += v.x; ly += v.y; lz += v.z; lw += v.w;
  }
  float Pl[4], Rl[4];
  {
    const float el_[4] = {elv.x, elv.y, elv.z, elv.w};
    const float lv_[4] = {lx, ly, lz, lw};
    #pragma unroll
    for (int h = 0; h < 4; ++h) {
      const float inv = 1.0f / lv_[h];   // > 0: diagonal of adj is 1
      Pl[h] = __builtin_amdgcn_exp2f(el_[h]) * inv;
      Rl[h] = __builtin_amdgcn_exp2f(0.2f * el_[h]) * inv;
    }
  }

  // window mask: 4 x 64-bit ballot words
  const unsigned long long* bp = adjB + (size_t)i * 64 + sw * 4;
  unsigned long long b0 = bp[0], b1 = bp[1], b2 = bp[2], b3 = bp[3];

  f4v acc[4];
  #pragma unroll
  for (int nf = 0; nf < 4; ++nf) acc[nf] = (f4v){0.f, 0.f, 0.f, 0.f};

  const s8v* vfp = (const s8v*)Vf;
  s8v Bc[4];
  #pragma unroll
  for (int nf = 0; nf < 4; ++nf)
    Bc[nf] = vfp[(size_t)((0 * 128 + sw * 8 + 0) * 4 + nf) * 64 + l];

  #pragma unroll 1
  for (int jc = 0; jc < 8; ++jc) {
    const unsigned sh = jc * 8 + q * 2;
    const unsigned t0 = (unsigned)(b0 >> sh) & 3u;
    const unsigned t1 = (unsigned)(b1 >> sh) & 3u;
    const unsigned t2 = (unsigned)(b2 >> sh) & 3u;
    const unsigned t3 = (unsigned)(b3 >> sh) & 3u;
    float bitf[8];
    bitf[0] = (float)(t0 & 1u); bitf[4] = (float)(t0 >> 1);
    bitf[1] = (float)(t1 & 1u); bitf[5] = (float)(t1 >> 1);
    bitf[2] = (float)(t2 & 1u); bitf[6] = (float)(t2 >> 1);
    bitf[3] = (float)(t3 & 1u); bitf[7] = (float)(t3 >> 1);

    #pragma unroll
    for (int h = 0; h < 4; ++h) {
      const int hn = (h < 3) ? h + 1 : 0;
      const int jcn = (h < 3) ? jc : jc + 1;
      s8v Bn[4];
      #pragma unroll
      for (int nf = 0; nf < 4; ++nf)
        Bn[nf] = vfp[(size_t)((hn * 128 + sw * 8 + jcn) * 4 + nf) * 64 + l];

      const float* cell = qs + (((w * 4 + h) * 8 + jc) * 4 + q) * 16;
      float4 q0  = *(const float4*)(cell);
      float4 q1  = *(const float4*)(cell + 4);
      float4 sv0 = *(const float4*)(cell + 8);
      float4 sv1 = *(const float4*)(cell + 12);
      const float Ph = Pl[h], Rh = Rl[h];
      float s0 = bitf[0] * fmaxf(Ph * q0.x, Rh * sv0.x);
      float s1 = bitf[1] * fmaxf(Ph * q0.y, Rh * sv0.y);
      float s2 = bitf[2] * fmaxf(Ph * q0.z, Rh * sv0.z);
      float s3 = bitf[3] * fmaxf(Ph * q0.w, Rh * sv0.w);
      float s4 = bitf[4] * fmaxf(Ph * q1.x, Rh * sv1.x);
      float s5 = bitf[5] * fmaxf(Ph * q1.y, Rh * sv1.y);
      float s6 = bitf[6] * fmaxf(Ph * q1.z, Rh * sv1.z);
      float s7 = bitf[7] * fmaxf(Ph * q1.w, Rh * sv1.w);
      union { unsigned u[4]; s8v v; } A;   // A-frag: row m, k = q*8+idx
      A.u[0] = pack2_rne(s0, s1);
      A.u[1] = pack2_rne(s2, s3);
      A.u[2] = pack2_rne(s4, s5);
      A.u[3] = pack2_rne(s6, s7);
      #pragma unroll
      for (int nf = 0; nf < 4; ++nf)
        acc[nf] = __builtin_amdgcn_mfma_f32_16x16x32_bf16(A.v, Bc[nf], acc[nf], 0, 0, 0);
      #pragma unroll
      for (int nf = 0; nf < 4; ++nf) Bc[nf] = Bn[nf];
    }
  }

  // merge 4 waves' tiles in LDS (reuse qs; f4v stride 20 -> conflict-free)
  __syncthreads();                     // all qs reads done
  if (w > 0) {
    float* dst = qs + ((w - 1) * 64 + l) * 20;
    #pragma unroll
    for (int nf = 0; nf < 4; ++nf)
      *(f4v*)(dst + nf * 4) = acc[nf];
  }
  __syncthreads();
  if (w == 0) {
    const float* src = qs + l * 20;
    #pragma unroll
    for (int nf = 0; nf < 4; ++nf) {
      f4v s = acc[nf];
      s += *(const f4v*)(src +    0 + nf * 4);   // wave1
      s += *(const f4v*)(src + 1280 + nf * 4);   // wave2
      s += *(const f4v*)(src + 2560 + nf * 4);   // wave3
      #pragma unroll
      for (int r = 0; r < 4; ++r) {
        int row = i0 + q * 4 + r;
        int col = nf * 16 + m;
        atomicAdd(&out[row * 64 + col], 0.25f * s[r]);
      }
    }
  }
}

extern "C" void kernel_launch(void* const* d_in, const int* in_sizes, int n_in,
                              void* d_out, int out_size, void* d_ws, size_t ws_size,
                              hipStream_t stream) {
  const float* x   = (const float*)d_in[0];   // (4096, 256)
  const float* adj = (const float*)d_in[1];   // (4096, 4096)
  const float* W   = (const float*)d_in[2];   // (256, 256)
  const float* a   = (const float*)d_in[3];   // (128, 1)
  float* out = (float*)d_out;                 // (4096, 64)

  char* ws = (char*)d_ws;
  unsigned short* Vf = (unsigned short*)ws;                  // 2 MB  bf16 fragment-ordered
  float* el4   = (float*)(ws + (2u << 20));                  // 64 KB [4096][4]
  float* Qr    = (float*)(ws + (2u << 20) + (64u << 10));    // 64 KB [4][4096]
  float* Sr    = (float*)(ws + (2u << 20) + (128u << 10));   // 64 KB [4][4096]
  float* lsumP = (float*)(ws + (2u << 20) + (192u << 10));   // 256 KB [4][4096][4]
  unsigned long long* adjB = (unsigned long long*)(ws + (2u << 20) + (448u << 10)); // 2 MB bits

  hipMemsetAsync(out, 0, (size_t)out_size * sizeof(float), stream);
  k1_proj<<<512, 256, 0, stream>>>(x, W, a, Vf, el4, Qr, Sr);
  k0_pack<<<dim3(1024, 4), 256, 0, stream>>>(adj, el4, Qr, Sr, adjB, lsumP);
  k2_attn<<<dim3(256, 4), 256, 0, stream>>>(adjB, Vf, el4, lsumP, Qr, Sr, out);
}

// Round 12
// 157.497 us; speedup vs baseline: 1.5163x; 1.0136x over previous
//
#include <hip/hip_runtime.h>
#include <hip/hip_bf16.h>

#define NN 4096
#define LOG2E 1.44269504088896340736f

typedef __attribute__((ext_vector_type(8))) short s8v;   // 8 x bf16
typedef __attribute__((ext_vector_type(4))) float f4v;   // mfma accumulator

__device__ __forceinline__ unsigned fu(float x){ union{float f;unsigned u;}z; z.f=x; return z.u; }
__device__ __forceinline__ unsigned short f2bf_rne(float x){
  unsigned u = fu(x);
  u += 0x7fffu + ((u >> 16) & 1u);
  return (unsigned short)(u >> 16);
}
__device__ __forceinline__ unsigned pack2_rne(float a, float b){
  return (unsigned)f2bf_rne(a) | ((unsigned)f2bf_rne(b) << 16);
}

// Kernel 1: h = x@W (fp32), write Vf in MFMA-fragment order (bf16),
// el' (x LOG2E) and factorized exponentials Qr=exp2(er'), Sr=exp2(0.2*er').
// W loads: depth-2 software pipeline.
__global__ __launch_bounds__(256) void k1_proj(
    const float* __restrict__ x, const float* __restrict__ W,
    const float* __restrict__ a, unsigned short* __restrict__ Vf,
    float* __restrict__ el4, float* __restrict__ Qr, float* __restrict__ Sr)
{
  __shared__ float4 xs[512];           // 8 rows x 256 cols fp32
  const int t = threadIdx.x;
  const int r0 = blockIdx.x * 8;
  const float4* xg = (const float4*)(x + (size_t)r0 * 256);
  xs[t] = xg[t];
  xs[t + 256] = xg[t + 256];
  __syncthreads();

  float acc[8] = {0.f,0.f,0.f,0.f,0.f,0.f,0.f,0.f};
  const float* Wp = W + t;             // column c = t
  float wa0 = Wp[0],    wa1 = Wp[256],  wa2 = Wp[512],  wa3 = Wp[768];
  float wb0 = Wp[1024], wb1 = Wp[1280], wb2 = Wp[1536], wb3 = Wp[1792];
  #pragma unroll 1
  for (int k4 = 0; k4 < 64; ++k4) {
    const int kn = (k4 + 2) & 63;      // depth-2 prefetch, wrap stays in-bounds
    float nw0 = Wp[kn*1024 +   0];
    float nw1 = Wp[kn*1024 + 256];
    float nw2 = Wp[kn*1024 + 512];
    float nw3 = Wp[kn*1024 + 768];
    #pragma unroll
    for (int r = 0; r < 8; ++r) {
      float4 xv = xs[r*64 + k4];       // broadcast LDS read
      acc[r] = fmaf(xv.x, wa0, acc[r]);
      acc[r] = fmaf(xv.y, wa1, acc[r]);
      acc[r] = fmaf(xv.z, wa2, acc[r]);
      acc[r] = fmaf(xv.w, wa3, acc[r]);
    }
    wa0 = wb0; wa1 = wb1; wa2 = wb2; wa3 = wb3;
    wb0 = nw0; wb1 = nw1; wb2 = nw2; wb3 = nw3;
  }

  // Vf write: thread t holds V[r0..r0+7][c=t] -> exactly one fragment chunk
  union { unsigned u[4]; s8v v; } pk;
  #pragma unroll
  for (int p = 0; p < 4; ++p)
    pk.u[p] = pack2_rne(acc[2*p], acc[2*p+1]);
  {
    const int hh = t >> 6, nf = (t >> 4) & 3, mm = t & 15;
    const int jblk = r0 >> 5, qq = (r0 >> 3) & 3;
    const size_t chunk = (size_t)(((hh * 128 + jblk) * 4 + nf) * 64 + qq * 16 + mm);
    *(s8v*)(Vf + chunk * 8) = pk.v;
  }

  // el/er: wave w == head h; lane f = t&63
  const int f = t & 63, h = t >> 6;
  const float al = a[f], ar = a[64 + f];
  #pragma unroll
  for (int r = 0; r < 8; ++r) {
    float v = acc[r] * al;
    float u = acc[r] * ar;
    #pragma unroll
    for (int off = 32; off > 0; off >>= 1) {
      v += __shfl_xor(v, off);
      u += __shfl_xor(u, off);
    }
    if (f == 0) {
      el4[(r0 + r) * 4 + h] = v * LOG2E;                     // [i][h] (x LOG2E)
      float up = u * LOG2E;
      Qr[h * NN + (r0 + r)] = __builtin_amdgcn_exp2f(up);        // [h][j]
      Sr[h * NN + (r0 + r)] = __builtin_amdgcn_exp2f(0.2f * up); // [h][j]
    }
  }
}

// Kernel 0: pack adj to bits AND softmax-denominator partials, 4 windows per
// block. grid (1024 row-groups, 4 window-groups), block 256 = 4 waves;
// wave = 1 row x 4 windows -> 4 independent adj float4 HBM loads in flight.
// Q/S for the 4 windows staged once in LDS (32 KB). One reduction per wave.
// Ballot order per 256-j window: bit for j in word (j&3) at position (j>>2).
// lsumP[p4][row][h] written with plain stores (no atomics, no memset).
__global__ __launch_bounds__(256, 4) void k0_pack(
    const float* __restrict__ adj, const float* __restrict__ el4,
    const float* __restrict__ Qr, const float* __restrict__ Sr,
    unsigned long long* __restrict__ adjB, float* __restrict__ lsumP)
{
  __shared__ float qsh[8192];          // 32KB: [k(4)][{Q,S}][h(4)][256]
  const int t = threadIdx.x;
  const int w = t >> 6, l = t & 63;
  const int row = blockIdx.x * 4 + w;
  const int p4 = blockIdx.y;
  const int jbase = p4 * 1024;

  // issue the 4 HBM adj loads first (deep MLP)
  const float* arow = adj + (size_t)row * NN + jbase + l * 4;
  float4 av0 = *(const float4*)(arow);
  float4 av1 = *(const float4*)(arow + 256);
  float4 av2 = *(const float4*)(arow + 512);
  float4 av3 = *(const float4*)(arow + 768);

  // cooperative stage: thread (h = t>>6, lane l), 4 windows x {Q,S}
  {
    const int h = t >> 6;
    #pragma unroll
    for (int k = 0; k < 4; ++k) {
      float4 qv = *(const float4*)(Qr + h * NN + jbase + k * 256 + l * 4);
      float4 sv = *(const float4*)(Sr + h * NN + jbase + k * 256 + l * 4);
      *(float4*)(qsh + ((k * 2 + 0) * 4 + h) * 256 + l * 4) = qv;
      *(float4*)(qsh + ((k * 2 + 1) * 4 + h) * 256 + l * 4) = sv;
    }
  }

  // pack bits (window = p4*4 + k)
  {
    unsigned long long* dst = adjB + (size_t)row * 64 + p4 * 16;
    const float4 avs[4] = {av0, av1, av2, av3};
    #pragma unroll
    for (int k = 0; k < 4; ++k) {
      unsigned long long b0 = __ballot(avs[k].x != 0.0f);
      unsigned long long b1 = __ballot(avs[k].y != 0.0f);
      unsigned long long b2 = __ballot(avs[k].z != 0.0f);
      unsigned long long b3 = __ballot(avs[k].w != 0.0f);
      if (l == 0) {
        dst[k * 4 + 0] = b0; dst[k * 4 + 1] = b1;
        dst[k * 4 + 2] = b2; dst[k * 4 + 3] = b3;
      }
    }
  }

  // P,R for this row (wave-uniform)
  float4 elv = *(const float4*)(el4 + row * 4);
  const float P[4] = { __builtin_amdgcn_exp2f(elv.x), __builtin_amdgcn_exp2f(elv.y),
                       __builtin_amdgcn_exp2f(elv.z), __builtin_amdgcn_exp2f(elv.w) };
  const float R[4] = { __builtin_amdgcn_exp2f(0.2f*elv.x), __builtin_amdgcn_exp2f(0.2f*elv.y),
                       __builtin_amdgcn_exp2f(0.2f*elv.z), __builtin_amdgcn_exp2f(0.2f*elv.w) };

  __syncthreads();

  float ls[4] = {0.f, 0.f, 0.f, 0.f};
  {
    const float4 avs[4] = {av0, av1, av2, av3};
    #pragma unroll
    for (int k = 0; k < 4; ++k) {
      const float4 av = avs[k];
      #pragma unroll
      for (int h = 0; h < 4; ++h) {
        float4 qv = *(const float4*)(qsh + ((k * 2 + 0) * 4 + h) * 256 + l * 4);
        float4 sv = *(const float4*)(qsh + ((k * 2 + 1) * 4 + h) * 256 + l * 4);
        float s;
        s = av.x * fmaxf(P[h] * qv.x, R[h] * sv.x);
        s = fmaf(av.y, fmaxf(P[h] * qv.y, R[h] * sv.y), s);
        s = fmaf(av.z, fmaxf(P[h] * qv.z, R[h] * sv.z), s);
        s = fmaf(av.w, fmaxf(P[h] * qv.w, R[h] * sv.w), s);
        ls[h] += s;
      }
    }
  }
  #pragma unroll
  for (int h = 0; h < 4; ++h) {
    float v = ls[h];
    #pragma unroll
    for (int off = 32; off > 0; off >>= 1) v += __shfl_xor(v, off);
    ls[h] = v;
  }
  if (l == 0)
    *(float4*)(lsumP + ((size_t)p4 * NN + row) * 4) = make_float4(ls[0], ls[1], ls[2], ls[3]);
}

// Kernel 2: masked-softmax-weighted PV via MFMA, heads folded, 32 rows/wave.
// grid (128 i-tiles of 32 rows, 4 splits), block 256 = 4 waves; wave w owns
// window sw = blockIdx.y*4 + w and BOTH 16-row sub-tiles -> every B-frag and
// every LDS Q/S read is reused for 2 sub-tiles (halves Vf L2 traffic).
// LDS merge across the 4 windows; wave 0 does the atomics (4/cell).
// lane: m = l&15 (row in sub-tile), q = l>>4 (k-quad).
__global__ __launch_bounds__(256, 2) void k2_attn(
    const unsigned long long* __restrict__ adjB, const unsigned short* __restrict__ Vf,
    const float* __restrict__ el4, const float* __restrict__ lsumP,
    const float* __restrict__ Qr, const float* __restrict__ Sr,
    float* __restrict__ out)
{
  __shared__ float qs[8192];           // 32KB: [w][h][jc][q][16] {Q[8],S[8]}; reused for merge
  const int t = threadIdx.x;
  const int w = t >> 6, l = t & 63;
  const int m = l & 15, q = l >> 4;
  const int i0 = blockIdx.x * 32;
  const int sw = blockIdx.y * 4 + w;   // this wave's 256-j window (0..15)
  const int jwin = sw * 256;

  // wave-private staging: no barrier needed before use
  {
    const int jc = l >> 3, qq = (l >> 1) & 3, hp = (l & 1) * 4;
    #pragma unroll
    for (int h = 0; h < 4; ++h) {
      float4 qv = *(const float4*)(Qr + h * NN + jwin + l * 4);
      float4 sv = *(const float4*)(Sr + h * NN + jwin + l * 4);
      float* cell = qs + (((w * 4 + h) * 8 + jc) * 4 + qq) * 16;
      *(float4*)(cell + hp) = qv;
      *(float4*)(cell + 8 + hp) = sv;
    }
  }

  // per-sub-tile row params: PL/RL inline from el4 + summed lsumP; masks
  float Pl[2][4], Rl[2][4];
  unsigned long long bm[2][4];
  #pragma unroll
  for (int s = 0; s < 2; ++s) {
    const int i = i0 + s * 16 + m;
    float4 elv = *(const float4*)(el4 + i * 4);
    float lx = 0.f, ly = 0.f, lz = 0.f, lw = 0.f;
    #pragma unroll
    for (int p = 0; p < 4; ++p) {
      float4 v = *(const float4*)(lsumP + ((size_t)p * NN + i) * 4);
      lx += v.x; ly += v.y; lz += v.z; lw += v.w;
    }
    const float el_[4] = {elv.x, elv.y, elv.z, elv.w};
    const float lv_[4] = {lx, ly, lz, lw};
    #pragma unroll
    for (int h = 0; h < 4; ++h) {
      const float inv = 1.0f / lv_[h];   // > 0: diagonal of adj is 1
      Pl[s][h] = __builtin_amdgcn_exp2f(el_[h]) * inv;
      Rl[s][h] = __builtin_amdgcn_exp2f(0.2f * el_[h]) * inv;
    }
    const unsigned long long* bp = adjB + (size_t)i * 64 + sw * 4;
    bm[s][0] = bp[0]; bm[s][1] = bp[1]; bm[s][2] = bp[2]; bm[s][3] = bp[3];
  }

  f4v acc[2][4];
  #pragma unroll
  for (int s = 0; s < 2; ++s)
    #pragma unroll
    for (int nf = 0; nf < 4; ++nf) acc[s][nf] = (f4v){0.f, 0.f, 0.f, 0.f};

  const s8v* vfp = (const s8v*)Vf;
  s8v Bc[4];
  #pragma unroll
  for (int nf = 0; nf < 4; ++nf)
    Bc[nf] = vfp[(size_t)((0 * 128 + sw * 8 + 0) * 4 + nf) * 64 + l];

  #pragma unroll 1
  for (int jc = 0; jc < 8; ++jc) {
    const unsigned sh = jc * 8 + q * 2;
    float bitf[2][8];
    #pragma unroll
    for (int s = 0; s < 2; ++s) {
      const unsigned t0 = (unsigned)(bm[s][0] >> sh) & 3u;
      const unsigned t1 = (unsigned)(bm[s][1] >> sh) & 3u;
      const unsigned t2 = (unsigned)(bm[s][2] >> sh) & 3u;
      const unsigned t3 = (unsigned)(bm[s][3] >> sh) & 3u;
      bitf[s][0] = (float)(t0 & 1u); bitf[s][4] = (float)(t0 >> 1);
      bitf[s][1] = (float)(t1 & 1u); bitf[s][5] = (float)(t1 >> 1);
      bitf[s][2] = (float)(t2 & 1u); bitf[s][6] = (float)(t2 >> 1);
      bitf[s][3] = (float)(t3 & 1u); bitf[s][7] = (float)(t3 >> 1);
    }

    #pragma unroll
    for (int h = 0; h < 4; ++h) {
      const int hn = (h < 3) ? h + 1 : 0;
      const int jcn = (h < 3) ? jc : jc + 1;
      s8v Bn[4];
      #pragma unroll
      for (int nf = 0; nf < 4; ++nf)
        Bn[nf] = vfp[(size_t)((hn * 128 + sw * 8 + jcn) * 4 + nf) * 64 + l];

      const float* cell = qs + (((w * 4 + h) * 8 + jc) * 4 + q) * 16;
      float4 q0  = *(const float4*)(cell);
      float4 q1  = *(const float4*)(cell + 4);
      float4 sv0 = *(const float4*)(cell + 8);
      float4 sv1 = *(const float4*)(cell + 12);
      #pragma unroll
      for (int s = 0; s < 2; ++s) {
        const float Ph = Pl[s][h], Rh = Rl[s][h];
        float s0 = bitf[s][0] * fmaxf(Ph * q0.x, Rh * sv0.x);
        float s1 = bitf[s][1] * fmaxf(Ph * q0.y, Rh * sv0.y);
        float s2 = bitf[s][2] * fmaxf(Ph * q0.z, Rh * sv0.z);
        float s3 = bitf[s][3] * fmaxf(Ph * q0.w, Rh * sv0.w);
        float s4 = bitf[s][4] * fmaxf(Ph * q1.x, Rh * sv1.x);
        float s5 = bitf[s][5] * fmaxf(Ph * q1.y, Rh * sv1.y);
        float s6 = bitf[s][6] * fmaxf(Ph * q1.z, Rh * sv1.z);
        float s7 = bitf[s][7] * fmaxf(Ph * q1.w, Rh * sv1.w);
        union { unsigned u[4]; s8v v; } A;   // A-frag: row m, k = q*8+idx
        A.u[0] = pack2_rne(s0, s1);
        A.u[1] = pack2_rne(s2, s3);
        A.u[2] = pack2_rne(s4, s5);
        A.u[3] = pack2_rne(s6, s7);
        #pragma unroll
        for (int nf = 0; nf < 4; ++nf)
          acc[s][nf] = __builtin_amdgcn_mfma_f32_16x16x32_bf16(A.v, Bc[nf], acc[s][nf], 0, 0, 0);
      }
      #pragma unroll
      for (int nf = 0; nf < 4; ++nf) Bc[nf] = Bn[nf];
    }
  }

  // merge 4 windows' accs in LDS (stride 36 floats, 16B aligned)
  __syncthreads();                     // all qs reads done
  if (w > 0) {
    float* dst = qs + ((w - 1) * 64 + l) * 36;
    #pragma unroll
    for (int s = 0; s < 2; ++s)
      #pragma unroll
      for (int nf = 0; nf < 4; ++nf)
        *(f4v*)(dst + (s * 4 + nf) * 4) = acc[s][nf];
  }
  __syncthreads();
  if (w == 0) {
    #pragma unroll
    for (int s = 0; s < 2; ++s)
      #pragma unroll
      for (int nf = 0; nf < 4; ++nf) {
        f4v sum = acc[s][nf];
        #pragma unroll
        for (int ww = 0; ww < 3; ++ww)
          sum += *(const f4v*)(qs + (ww * 64 + l) * 36 + (s * 4 + nf) * 4);
        #pragma unroll
        for (int r = 0; r < 4; ++r) {
          int row = i0 + s * 16 + q * 4 + r;
          int col = nf * 16 + m;
          atomicAdd(&out[row * 64 + col], 0.25f * sum[r]);
        }
      }
  }
}

extern "C" void kernel_launch(void* const* d_in, const int* in_sizes, int n_in,
                              void* d_out, int out_size, void* d_ws, size_t ws_size,
                              hipStream_t stream) {
  const float* x   = (const float*)d_in[0];   // (4096, 256)
  const float* adj = (const float*)d_in[1];   // (4096, 4096)
  const float* W   = (const float*)d_in[2];   // (256, 256)
  const float* a   = (const float*)d_in[3];   // (128, 1)
  float* out = (float*)d_out;                 // (4096, 64)

  char* ws = (char*)d_ws;
  unsigned short* Vf = (unsigned short*)ws;                  // 2 MB  bf16 fragment-ordered
  float* el4   = (float*)(ws + (2u << 20));                  // 64 KB [4096][4]
  float* Qr    = (float*)(ws + (2u << 20) + (64u << 10));    // 64 KB [4][4096]
  float* Sr    = (float*)(ws + (2u << 20) + (128u << 10));   // 64 KB [4][4096]
  float* lsumP = (float*)(ws + (2u << 20) + (192u << 10));   // 256 KB [4][4096][4]
  unsigned long long* adjB = (unsigned long long*)(ws + (2u << 20) + (448u << 10)); // 2 MB bits

  hipMemsetAsync(out, 0, (size_t)out_size * sizeof(float), stream);
  k1_proj<<<512, 256, 0, stream>>>(x, W, a, Vf, el4, Qr, Sr);
  k0_pack<<<dim3(1024, 4), 256, 0, stream>>>(adj, el4, Qr, Sr, adjB, lsumP);
  k2_attn<<<dim3(128, 4), 256, 0, stream>>>(adjB, Vf, el4, lsumP, Qr, Sr, out);
}